// Round 1
// baseline (3163.678 us; speedup 1.0000x reference)
//
#include <hip/hip_runtime.h>

#define D 128
typedef unsigned long long u64;

// ---------------- graph prep ----------------

__global__ __launch_bounds__(256) void k_hist(const int* __restrict__ dst, int* __restrict__ deg, int E){
  int e = blockIdx.x*256 + threadIdx.x;
  if (e < E) atomicAdd(&deg[dst[e]], 1);
}

__global__ __launch_bounds__(1024) void k_scan(const int* __restrict__ deg, int* __restrict__ off,
                                               int* __restrict__ cur, int n){
  __shared__ int wsum[16];
  __shared__ int carry_sh;
  int t = threadIdx.x, lane = t & 63, wid = t >> 6;
  if (t == 0) carry_sh = 0;
  __syncthreads();
  const int TILE = 4096;
  for (int base = 0; base < n; base += TILE){
    int idx = base + t*4;
    int v0 = (idx+0 < n)? deg[idx+0] : 0;
    int v1 = (idx+1 < n)? deg[idx+1] : 0;
    int v2 = (idx+2 < n)? deg[idx+2] : 0;
    int v3 = (idx+3 < n)? deg[idx+3] : 0;
    int tsum = v0+v1+v2+v3;
    int sc = tsum;                       // inclusive wave scan
    for (int o=1;o<64;o<<=1){ int u = __shfl_up(sc,o); if (lane>=o) sc += u; }
    if (lane == 63) wsum[wid] = sc;
    __syncthreads();
    if (wid == 0 && lane < 16){
      int ws = wsum[lane];
      int s2 = ws;
      for (int o=1;o<16;o<<=1){ int u = __shfl_up(s2,o); if (lane>=o) s2 += u; }
      wsum[lane] = s2 - ws;              // exclusive wave offsets
    }
    __syncthreads();
    int excl = carry_sh + wsum[wid] + sc - tsum;
    int run = excl;
    if (idx+0 < n){ off[idx+0]=run; cur[idx+0]=run; run+=v0; }
    if (idx+1 < n){ off[idx+1]=run; cur[idx+1]=run; run+=v1; }
    if (idx+2 < n){ off[idx+2]=run; cur[idx+2]=run; run+=v2; }
    if (idx+3 < n){ off[idx+3]=run; cur[idx+3]=run; run+=v3; }
    __syncthreads();
    if (t == 1023) carry_sh = excl + tsum;   // old carry + tile total
    __syncthreads();
  }
  if (t == 0) off[n] = carry_sh;
}

__global__ __launch_bounds__(256) void k_fill(const int* __restrict__ src, const int* __restrict__ dst,
                                              int* __restrict__ cur, int* __restrict__ csr, int E){
  int e = blockIdx.x*256 + threadIdx.x;
  if (e < E){ int p = atomicAdd(&cur[dst[e]], 1); csr[p] = src[e]; }
}

// ---------------- per-layer small math ----------------

// xsum[j] = sum_n deg[n]*x[n][j]   (f64 accumulate)
__global__ __launch_bounds__(256) void k_xsum(const float* __restrict__ x, const int* __restrict__ deg,
                                              double* __restrict__ xsum, int N){
  int j = threadIdx.x & 127;
  int sub = threadIdx.x >> 7;
  double a = 0.0;
  for (int n = blockIdx.x*2 + sub; n < N; n += gridDim.x*2){
    int dg = deg[n];
    if (dg) a += (double)dg * (double)x[(u64)n*D + j];
  }
  atomicAdd(&xsum[j], a);
}

// ksum = xsum@Wk + E*bk ; t = rel@ksum ; c = scale*Wq@t ; c0 = scale*bq.t
__global__ __launch_bounds__(128) void k_coef(const double* __restrict__ xsum, const float* __restrict__ Wk,
                                              const float* __restrict__ bk, const float* __restrict__ rel,
                                              const float* __restrict__ Wq, const float* __restrict__ bq,
                                              int E, double* __restrict__ c, double* __restrict__ c0){
  __shared__ double sh[128];
  __shared__ double xs[128];
  int j = threadIdx.x;
  xs[j] = xsum[j];
  __syncthreads();
  double ks = (double)E * (double)bk[j];
  for (int d=0; d<128; ++d) ks += xs[d] * (double)Wk[d*128+j];
  sh[j] = ks;
  __syncthreads();
  double tmp = 0.0;
  for (int cc=0; cc<128; ++cc) tmp += (double)rel[j*128+cc] * sh[cc];
  __syncthreads();
  sh[j] = tmp;
  __syncthreads();
  const double scale = 0.08838834764831843;  // 1/sqrt(128)
  double cv = 0.0;
  for (int k2=0;k2<128;++k2) cv += (double)Wq[j*128+k2] * sh[k2];
  c[j] = cv * scale;
  if (j == 0){
    double z = 0.0;
    for (int k2=0;k2<128;++k2) z += (double)bq[k2] * sh[k2];
    *c0 = z * scale;
  }
}

// M = Wq @ Wk^T ; u1 = Wq@bk + Wk@bq ; b0 = bq.bk
__global__ __launch_bounds__(128) void k_prepM(const float* __restrict__ Wq, const float* __restrict__ Wk,
                                               const float* __restrict__ bq, const float* __restrict__ bk,
                                               float* __restrict__ M, float* __restrict__ u1, float* __restrict__ b0){
  int a = blockIdx.x, b = threadIdx.x;
  __shared__ float qrow[128];
  qrow[b] = Wq[a*128+b];
  __syncthreads();
  const float* krow = Wk + b*128;
  float acc = 0.f;
  for (int j=0;j<128;++j) acc += qrow[j]*krow[j];
  M[a*128+b] = acc;
  if (b == 0){
    float s1 = 0.f;
    for (int j=0;j<128;++j) s1 += Wq[a*128+j]*bk[j] + Wk[a*128+j]*bq[j];
    u1[a] = s1;
    if (a == 0){
      float z = 0.f;
      for (int j=0;j<128;++j) z += bq[j]*bk[j];
      *b0 = z;
    }
  }
}

// s[n] = x[n].c + c0  (f64), one wave per row
__global__ __launch_bounds__(256) void k_sdot(const float* __restrict__ x, const double* __restrict__ c,
                                              const double* __restrict__ c0, double* __restrict__ s, int N){
  int gid = blockIdx.x*256 + threadIdx.x;
  int wv = gid >> 6, lane = gid & 63;
  if (wv >= N) return;
  const float* xr = x + (u64)wv*D;
  double p = (double)xr[lane]*c[lane] + (double)xr[lane+64]*c[lane+64];
  for (int o=32;o;o>>=1) p += __shfl_xor(p, o);
  if (lane == 0) s[wv] = p + *c0;
}

// ---------------- row GEMMs ----------------

// out[row] = x[row]@W + bias  (+ x[row] if resid) ; thread-per-row, acc[128] in VGPRs
__global__ __launch_bounds__(256) void k_rowgemm(const float* __restrict__ x, const float* __restrict__ W,
                                                 const float* __restrict__ bias, float* __restrict__ out,
                                                 int N, int resid){
  int row = blockIdx.x*256 + threadIdx.x;
  if (row >= N) return;
  const float4* xr = (const float4*)(x + (u64)row*D);
  float acc[D];
#pragma unroll
  for (int j=0;j<D;++j) acc[j] = 0.f;
  for (int d0=0; d0<D; d0+=4){
    float4 xv = xr[d0>>2];
    const float* w0 = W + d0*D;
#pragma unroll
    for (int j=0;j<D;++j){
      float a = acc[j];
      a = fmaf(xv.x, w0[j],       a);
      a = fmaf(xv.y, w0[D+j],     a);
      a = fmaf(xv.z, w0[2*D+j],   a);
      a = fmaf(xv.w, w0[3*D+j],   a);
      acc[j] = a;
    }
  }
  float4* orow = (float4*)(out + (u64)row*D);
#pragma unroll
  for (int j=0;j<D;j+=4){
    float4 o;
    o.x = acc[j]   + bias[j];
    o.y = acc[j+1] + bias[j+1];
    o.z = acc[j+2] + bias[j+2];
    o.w = acc[j+3] + bias[j+3];
    if (resid){
      float4 xv = xr[j>>2];
      o.x += xv.x; o.y += xv.y; o.z += xv.z; o.w += xv.w;
    }
    orow[j>>2] = o;
  }
}

// l[n] = scale*( x M x^T + x.u1 + b0 )
__global__ __launch_bounds__(256) void k_quadform(const float* __restrict__ x, const float* __restrict__ M,
                                                  const float* __restrict__ u1, const float* __restrict__ b0,
                                                  float* __restrict__ lo, int N){
  int row = blockIdx.x*256 + threadIdx.x;
  if (row >= N) return;
  const float4* xr = (const float4*)(x + (u64)row*D);
  float acc[D];
#pragma unroll
  for (int j=0;j<D;++j) acc[j] = 0.f;
  for (int d0=0; d0<D; d0+=4){
    float4 xv = xr[d0>>2];
    const float* m0 = M + d0*D;
#pragma unroll
    for (int j=0;j<D;++j){
      float a = acc[j];
      a = fmaf(xv.x, m0[j],       a);
      a = fmaf(xv.y, m0[D+j],     a);
      a = fmaf(xv.z, m0[2*D+j],   a);
      a = fmaf(xv.w, m0[3*D+j],   a);
      acc[j] = a;
    }
  }
  float dot = 0.f, dotu = 0.f;
#pragma unroll
  for (int j=0;j<D;j+=4){
    float4 xv = xr[j>>2];
    dot  += acc[j]*xv.x + acc[j+1]*xv.y + acc[j+2]*xv.z + acc[j+3]*xv.w;
    dotu += u1[j]*xv.x  + u1[j+1]*xv.y  + u1[j+2]*xv.z  + u1[j+3]*xv.w;
  }
  lo[row] = 0.08838834764831843f * (dot + dotu + *b0);
}

// Zself = sum_n exp(l[n])   (logits are O(1), no max needed)
__global__ __launch_bounds__(256) void k_zself(const float* __restrict__ l, double* __restrict__ Z, int N){
  int stride = gridDim.x*256;
  double a = 0.0;
  for (int n = blockIdx.x*256 + threadIdx.x; n < N; n += stride) a += (double)expf(l[n]);
  for (int o=32;o;o>>=1) a += __shfl_xor(a, o);
  if ((threadIdx.x & 63) == 0) atomicAdd(Z, a);
}

// ---------------- aggregation: one wave per dst node ----------------

__global__ __launch_bounds__(256) void k_agg(const int* __restrict__ off, const int* __restrict__ csr,
                                             const double* __restrict__ s, const float* __restrict__ vsrc,
                                             const float* __restrict__ lself, const double* __restrict__ Zself,
                                             const float* __restrict__ vself, float* __restrict__ out, int N){
  int gid = blockIdx.x*256 + threadIdx.x;
  int n = gid >> 6, lane = gid & 63;
  if (n >= N) return;
  int beg = off[n], end = off[n+1];
  float ax = 0.f, ay = 0.f;
  if (end > beg){
    double m = -1e300;
    for (int e=beg;e<end;++e){ double sv = s[csr[e]]; m = sv > m ? sv : m; }
    float Zl = 0.f;
    for (int e=beg;e<end;++e) Zl += expf((float)(s[csr[e]] - m));
    float inv = 1.f / (Zl * (float)(end - beg));
    for (int e=beg;e<end;++e){
      int src = csr[e];
      float w = expf((float)(s[src] - m)) * inv;
      float2 v = ((const float2*)(vsrc + (u64)src*D))[lane];
      ax = fmaf(w, v.x, ax);
      ay = fmaf(w, v.y, ay);
    }
  }
  float a = expf(lself[n]) / (float)(*Zself);
  float2 vs = ((const float2*)(vself + (u64)n*D))[lane];
  ax = fmaf(a, vs.x, ax);
  ay = fmaf(a, vs.y, ay);
  ((float2*)(out + (u64)n*D))[lane] = make_float2(ax, ay);
}

// ---------------- launch ----------------

extern "C" void kernel_launch(void* const* d_in, const int* in_sizes, int n_in,
                              void* d_out, int out_size, void* d_ws, size_t ws_size,
                              hipStream_t stream){
  const float* x_user = (const float*)d_in[0];
  const float* x_item = (const float*)d_in[1];
  const int*   ei_u2i = (const int*)d_in[2];   // [2,E]: row0 src(user), row1 dst(item)
  const int*   ei_i2u = (const int*)d_in[3];   // [2,E]: row0 src(item), row1 dst(user)
  const float* qkv_w  = (const float*)d_in[4]; // [2,2,3,D,D]
  const float* qkv_b  = (const float*)d_in[5]; // [2,2,3,D]
  const float* rel_w  = (const float*)d_in[6]; // [2,2,D,D]
  const float* self_w = (const float*)d_in[7]; // [2,D,D]
  const float* self_b = (const float*)d_in[8]; // [2,D]

  const int N = in_sizes[0] / D;
  const int E = in_sizes[2] / 2;
  float* outU = (float*)d_out;
  float* outI = outU + (u64)N*D;

  char* p = (char*)d_ws;
  auto alloc = [&](size_t bytes)->char*{ char* r = p; p += (bytes + 255)/256*256; return r; };
  float*  v_u  = (float*) alloc((u64)N*D*4);
  float*  v_i  = (float*) alloc((u64)N*D*4);
  double* s_u  = (double*)alloc((u64)N*8);
  double* s_i  = (double*)alloc((u64)N*8);
  float*  l_u  = (float*) alloc((u64)N*4);
  float*  l_i  = (float*) alloc((u64)N*4);
  int*    deg_u= (int*)   alloc((u64)N*4);
  int*    deg_i= (int*)   alloc((u64)N*4);
  int*    off_u= (int*)   alloc((u64)(N+1)*4);
  int*    off_i= (int*)   alloc((u64)(N+1)*4);
  int*    cur_u= (int*)   alloc((u64)N*4);
  int*    cur_i= (int*)   alloc((u64)N*4);
  int*    csr_u= (int*)   alloc((u64)E*4);
  int*    csr_i= (int*)   alloc((u64)E*4);
  float*  M_u  = (float*) alloc(D*D*4);
  float*  M_i  = (float*) alloc(D*D*4);
  float*  u1_u = (float*) alloc(D*4);
  float*  u1_i = (float*) alloc(D*4);
  float*  b0_u = (float*) alloc(256);
  float*  b0_i = (float*) alloc(256);
  char* zbase = p;                       // zero-init group
  double* xsum_u = (double*)alloc(D*8);
  double* xsum_i = (double*)alloc(D*8);
  double* Zs_u   = (double*)alloc(256);
  double* Zs_i   = (double*)alloc(256);
  size_t zbytes = (size_t)(p - zbase);
  double* c_i  = (double*)alloc(D*8);
  double* c0_i = (double*)alloc(256);
  double* c_u  = (double*)alloc(D*8);
  double* c0_u = (double*)alloc(256);

  auto w   = [&](int l,int t,int j){ return qkv_w + (u64)((l*2+t)*3+j)*D*D; };
  auto bb  = [&](int l,int t,int j){ return qkv_b + (u64)((l*2+t)*3+j)*D; };
  auto rel = [&](int l,int et){ return rel_w + (u64)(l*2+et)*D*D; };

  const int gE = (E + 255)/256;
  hipMemsetAsync(deg_u, 0, (u64)N*4, stream);
  hipMemsetAsync(deg_i, 0, (u64)N*4, stream);
  k_hist<<<gE,256,0,stream>>>(ei_i2u + E, deg_u, E);
  k_hist<<<gE,256,0,stream>>>(ei_u2i + E, deg_i, E);
  k_scan<<<1,1024,0,stream>>>(deg_u, off_u, cur_u, N);
  k_scan<<<1,1024,0,stream>>>(deg_i, off_i, cur_i, N);
  k_fill<<<gE,256,0,stream>>>(ei_i2u, ei_i2u + E, cur_u, csr_u, E);
  k_fill<<<gE,256,0,stream>>>(ei_u2i, ei_u2i + E, cur_i, csr_i, E);

  const int gRow  = (N + 255)/256;
  const int gWave = (N + 3)/4;
  for (int L=0; L<2; ++L){
    const float* xu = L ? outU : x_user;
    const float* xi = L ? outI : x_item;
    hipMemsetAsync(zbase, 0, zbytes, stream);
    k_xsum<<<256,256,0,stream>>>(xu, deg_u, xsum_u, N);
    k_xsum<<<256,256,0,stream>>>(xi, deg_i, xsum_i, N);
    // out_u direction: ksum over user-k, c for item nodes
    k_coef<<<1,128,0,stream>>>(xsum_u, w(L,0,1), bb(L,0,1), rel(L,1), w(L,1,0), bb(L,1,0), E, c_i, c0_i);
    // out_i direction: ksum over item-k, c for user nodes
    k_coef<<<1,128,0,stream>>>(xsum_i, w(L,1,1), bb(L,1,1), rel(L,0), w(L,0,0), bb(L,0,0), E, c_u, c0_u);
    k_prepM<<<128,128,0,stream>>>(w(L,0,0), w(L,0,1), bb(L,0,0), bb(L,0,1), M_u, u1_u, b0_u);
    k_prepM<<<128,128,0,stream>>>(w(L,1,0), w(L,1,1), bb(L,1,0), bb(L,1,1), M_i, u1_i, b0_i);
    k_sdot<<<gWave,256,0,stream>>>(xi, c_i, c0_i, s_i, N);
    k_sdot<<<gWave,256,0,stream>>>(xu, c_u, c0_u, s_u, N);
    k_rowgemm<<<gRow,256,0,stream>>>(xu, w(L,0,2), bb(L,0,2), v_u, N, 0);
    k_rowgemm<<<gRow,256,0,stream>>>(xi, w(L,1,2), bb(L,1,2), v_i, N, 0);
    k_quadform<<<gRow,256,0,stream>>>(xu, M_u, u1_u, b0_u, l_u, N);
    k_quadform<<<gRow,256,0,stream>>>(xi, M_i, u1_i, b0_i, l_i, N);
    k_zself<<<512,256,0,stream>>>(l_u, Zs_u, N);
    k_zself<<<512,256,0,stream>>>(l_i, Zs_i, N);
    k_agg<<<gWave,256,0,stream>>>(off_u, csr_u, s_i, v_i, l_u, Zs_u, v_u, outU, N);
    k_agg<<<gWave,256,0,stream>>>(off_i, csr_i, s_u, v_u, l_i, Zs_i, v_i, outI, N);
  }
  k_rowgemm<<<gRow,256,0,stream>>>(outU, self_w,        self_b,     outU, N, 1);
  k_rowgemm<<<gRow,256,0,stream>>>(outI, self_w + D*D,  self_b + D, outI, N, 1);
}

// Round 2
// 2034.530 us; speedup vs baseline: 1.5550x; 1.5550x over previous
//
#include <hip/hip_runtime.h>

#define D 128
typedef unsigned long long u64;

// ---------------- graph prep ----------------

__global__ __launch_bounds__(256) void k_hist(const int* __restrict__ dstA, const int* __restrict__ dstB,
                                              int* __restrict__ deg, int N, int E){
  int e = blockIdx.x*256 + threadIdx.x;
  int y = blockIdx.y;
  const int* d = y ? dstB : dstA;
  if (e < E) atomicAdd(&deg[(u64)y*N + d[e]], 1);
}

__global__ __launch_bounds__(1024) void k_scan(const int* __restrict__ degA, int* __restrict__ offA,
                                               int* __restrict__ curA, int n){
  int y = blockIdx.y;
  const int* deg = degA + (u64)y*n;
  int* off = offA + (u64)y*(n+1);
  int* cur = curA + (u64)y*n;
  __shared__ int wsum[16];
  __shared__ int carry_sh;
  int t = threadIdx.x, lane = t & 63, wid = t >> 6;
  if (t == 0) carry_sh = 0;
  __syncthreads();
  const int TILE = 4096;
  for (int base = 0; base < n; base += TILE){
    int idx = base + t*4;
    int v0 = (idx+0 < n)? deg[idx+0] : 0;
    int v1 = (idx+1 < n)? deg[idx+1] : 0;
    int v2 = (idx+2 < n)? deg[idx+2] : 0;
    int v3 = (idx+3 < n)? deg[idx+3] : 0;
    int tsum = v0+v1+v2+v3;
    int sc = tsum;                       // inclusive wave scan
    for (int o=1;o<64;o<<=1){ int u = __shfl_up(sc,o); if (lane>=o) sc += u; }
    if (lane == 63) wsum[wid] = sc;
    __syncthreads();
    if (wid == 0 && lane < 16){
      int ws = wsum[lane];
      int s2 = ws;
      for (int o=1;o<16;o<<=1){ int u = __shfl_up(s2,o); if (lane>=o) s2 += u; }
      wsum[lane] = s2 - ws;              // exclusive wave offsets
    }
    __syncthreads();
    int excl = carry_sh + wsum[wid] + sc - tsum;
    int run = excl;
    if (idx+0 < n){ off[idx+0]=run; cur[idx+0]=run; run+=v0; }
    if (idx+1 < n){ off[idx+1]=run; cur[idx+1]=run; run+=v1; }
    if (idx+2 < n){ off[idx+2]=run; cur[idx+2]=run; run+=v2; }
    if (idx+3 < n){ off[idx+3]=run; cur[idx+3]=run; run+=v3; }
    __syncthreads();
    if (t == 1023) carry_sh = excl + tsum;
    __syncthreads();
  }
  if (t == 0) off[n] = carry_sh;
}

__global__ __launch_bounds__(256) void k_fill(const int* __restrict__ eiA, const int* __restrict__ eiB,
                                              int* __restrict__ cur, int* __restrict__ csr, int N, int E){
  int e = blockIdx.x*256 + threadIdx.x;
  int y = blockIdx.y;
  const int* ei = y ? eiB : eiA;
  if (e < E){
    int p = atomicAdd(&cur[(u64)y*N + ei[E + e]], 1);
    csr[(u64)y*E + p] = ei[e];
  }
}

// ---------------- per-layer small math ----------------

// xsum[y][j] = sum_n deg[y][n]*x_y[n][j]   (f64 accumulate)
__global__ __launch_bounds__(256) void k_xsum(const float* __restrict__ x0, const float* __restrict__ x1,
                                              const int* __restrict__ deg, double* __restrict__ xsum, int N){
  int y = blockIdx.y;
  const float* x = y ? x1 : x0;
  const int* dg = deg + (u64)y*N;
  double* xs = xsum + y*128;
  int j = threadIdx.x & 127;
  int sub = threadIdx.x >> 7;
  double a = 0.0;
  for (int n = blockIdx.x*2 + sub; n < N; n += gridDim.x*2){
    int d = dg[n];
    if (d) a += (double)d * (double)x[(u64)n*D + j];
  }
  atomicAdd(&xs[j], a);
}

// per src-type t: ksum = xsum[1-t]@Wk(1-t) + E*bk ; tmp = rel(t)@ksum ; c[t] = scale*Wq(t)@tmp
__global__ __launch_bounds__(128) void k_coef(const double* __restrict__ xsum, const float* __restrict__ qkv_w,
                                              const float* __restrict__ qkv_b, const float* __restrict__ rel_w,
                                              int L, int E, double* __restrict__ c, double* __restrict__ c0){
  int t = blockIdx.x;       // src node type whose coefficients we compute
  const float* Wk = qkv_w + (u64)((L*2 + (1-t))*3 + 1)*D*D;
  const float* bk = qkv_b + (u64)((L*2 + (1-t))*3 + 1)*D;
  const float* Wq = qkv_w + (u64)((L*2 + t)*3 + 0)*D*D;
  const float* bq = qkv_b + (u64)((L*2 + t)*3 + 0)*D;
  const float* rel = rel_w + (u64)(L*2 + t)*D*D;
  const double* xs0 = xsum + (1-t)*128;

  __shared__ double sh[128];
  __shared__ double xs[128];
  int j = threadIdx.x;
  xs[j] = xs0[j];
  __syncthreads();
  double ks = (double)E * (double)bk[j];
  for (int d=0; d<128; ++d) ks += xs[d] * (double)Wk[d*128+j];
  sh[j] = ks;
  __syncthreads();
  double tmp = 0.0;
  for (int cc=0; cc<128; ++cc) tmp += (double)rel[j*128+cc] * sh[cc];
  __syncthreads();
  sh[j] = tmp;
  __syncthreads();
  const double scale = 0.08838834764831843;  // 1/sqrt(128)
  double cv = 0.0;
  for (int k2=0;k2<128;++k2) cv += (double)Wq[j*128+k2] * sh[k2];
  c[t*128 + j] = cv * scale;
  if (j == 0){
    double z = 0.0;
    for (int k2=0;k2<128;++k2) z += (double)bq[k2] * sh[k2];
    c0[t] = z * scale;
  }
}

// M[y] = Wq@Wk^T ; u1[y] = Wq@bk + Wk@bq ; b0[y] = bq.bk   (self-attention quadform)
__global__ __launch_bounds__(128) void k_prepM(const float* __restrict__ qkv_w, const float* __restrict__ qkv_b,
                                               int L, float* __restrict__ M, float* __restrict__ u1,
                                               float* __restrict__ b0){
  int y = blockIdx.y;
  const float* Wq = qkv_w + (u64)((L*2 + y)*3 + 0)*D*D;
  const float* Wk = qkv_w + (u64)((L*2 + y)*3 + 1)*D*D;
  const float* bq = qkv_b + (u64)((L*2 + y)*3 + 0)*D;
  const float* bk = qkv_b + (u64)((L*2 + y)*3 + 1)*D;
  int a = blockIdx.x, b = threadIdx.x;
  __shared__ float qrow[128];
  qrow[b] = Wq[a*128+b];
  __syncthreads();
  const float* krow = Wk + b*128;
  float acc = 0.f;
  for (int j=0;j<128;++j) acc += qrow[j]*krow[j];
  M[(u64)y*D*D + a*128 + b] = acc;
  if (b == 0){
    float s1 = 0.f;
    for (int j=0;j<128;++j) s1 += Wq[a*128+j]*bk[j] + Wk[a*128+j]*bq[j];
    u1[y*D + a] = s1;
    if (a == 0){
      float z = 0.f;
      for (int j=0;j<128;++j) z += bq[j]*bk[j];
      b0[y] = z;
    }
  }
}

// ---------------- row GEMMs ----------------

// v[y][row] = x_y[row]@Wv + bv ; s[y][row] = x_y[row].c[y] + c0[y]  (f64)
__global__ __launch_bounds__(256) void k_rowv(const float* __restrict__ x0, const float* __restrict__ x1,
                                              const float* __restrict__ qkv_w, const float* __restrict__ qkv_b,
                                              int L, const double* __restrict__ c, const double* __restrict__ c0,
                                              float* __restrict__ v, double* __restrict__ s, int N){
  int row = blockIdx.x*256 + threadIdx.x;
  if (row >= N) return;
  int y = blockIdx.y;
  const float* x = y ? x1 : x0;
  const float* W = qkv_w + (u64)((L*2 + y)*3 + 2)*D*D;
  const float* bias = qkv_b + (u64)((L*2 + y)*3 + 2)*D;
  const double* cc = c + y*128;

  const float4* xr = (const float4*)(x + (u64)row*D);
  float acc[D];
#pragma unroll
  for (int j=0;j<D;++j) acc[j] = 0.f;
  double sacc = 0.0;
  for (int d0=0; d0<D; d0+=4){
    float4 xv = xr[d0>>2];
    const float* w0 = W + d0*D;
    sacc += (double)xv.x*cc[d0] + (double)xv.y*cc[d0+1] + (double)xv.z*cc[d0+2] + (double)xv.w*cc[d0+3];
#pragma unroll
    for (int j=0;j<D;++j){
      float a = acc[j];
      a = fmaf(xv.x, w0[j],       a);
      a = fmaf(xv.y, w0[D+j],     a);
      a = fmaf(xv.z, w0[2*D+j],   a);
      a = fmaf(xv.w, w0[3*D+j],   a);
      acc[j] = a;
    }
  }
  s[(u64)y*N + row] = sacc + c0[y];
  float4* orow = (float4*)(v + (u64)y*N*D + (u64)row*D);
#pragma unroll
  for (int j=0;j<D;j+=4){
    float4 o;
    o.x = acc[j]   + bias[j];
    o.y = acc[j+1] + bias[j+1];
    o.z = acc[j+2] + bias[j+2];
    o.w = acc[j+3] + bias[j+3];
    orow[j>>2] = o;
  }
}

// out[y][row] = io[y][row]@W_self[y] + b_self[y] + io[y][row]   (in place, final)
__global__ __launch_bounds__(256) void k_rowres(float* __restrict__ io, const float* __restrict__ self_w,
                                                const float* __restrict__ self_b, int N){
  int row = blockIdx.x*256 + threadIdx.x;
  if (row >= N) return;
  int y = blockIdx.y;
  float* xbase = io + (u64)y*N*D;
  const float* W = self_w + (u64)y*D*D;
  const float* bias = self_b + y*D;
  const float4* xr = (const float4*)(xbase + (u64)row*D);
  float acc[D];
#pragma unroll
  for (int j=0;j<D;++j) acc[j] = 0.f;
  for (int d0=0; d0<D; d0+=4){
    float4 xv = xr[d0>>2];
    const float* w0 = W + d0*D;
#pragma unroll
    for (int j=0;j<D;++j){
      float a = acc[j];
      a = fmaf(xv.x, w0[j],       a);
      a = fmaf(xv.y, w0[D+j],     a);
      a = fmaf(xv.z, w0[2*D+j],   a);
      a = fmaf(xv.w, w0[3*D+j],   a);
      acc[j] = a;
    }
  }
  float4* orow = (float4*)(xbase + (u64)row*D);
#pragma unroll
  for (int j=0;j<D;j+=4){
    float4 xv = xr[j>>2];
    float4 o;
    o.x = acc[j]   + bias[j]   + xv.x;
    o.y = acc[j+1] + bias[j+1] + xv.y;
    o.z = acc[j+2] + bias[j+2] + xv.z;
    o.w = acc[j+3] + bias[j+3] + xv.w;
    orow[j>>2] = o;
  }
}

// l[y][n] = scale*( x M x^T + x.u1 + b0 ) ; Z[y] += sum exp(l)  (fused zself)
__global__ __launch_bounds__(256) void k_qz(const float* __restrict__ x0, const float* __restrict__ x1,
                                            const float* __restrict__ M, const float* __restrict__ u1,
                                            const float* __restrict__ b0, float* __restrict__ lo,
                                            double* __restrict__ Z, int N){
  int row = blockIdx.x*256 + threadIdx.x;
  int y = blockIdx.y;
  const float* x = y ? x1 : x0;
  const float* Mp = M + (u64)y*D*D;
  const float* u1p = u1 + y*D;
  float lval = 0.f;
  if (row < N){
    const float4* xr = (const float4*)(x + (u64)row*D);
    float acc[D];
#pragma unroll
    for (int j=0;j<D;++j) acc[j] = 0.f;
    for (int d0=0; d0<D; d0+=4){
      float4 xv = xr[d0>>2];
      const float* m0 = Mp + d0*D;
#pragma unroll
      for (int j=0;j<D;++j){
        float a = acc[j];
        a = fmaf(xv.x, m0[j],       a);
        a = fmaf(xv.y, m0[D+j],     a);
        a = fmaf(xv.z, m0[2*D+j],   a);
        a = fmaf(xv.w, m0[3*D+j],   a);
        acc[j] = a;
      }
    }
    float dot = 0.f, dotu = 0.f;
#pragma unroll
    for (int j=0;j<D;j+=4){
      float4 xv = xr[j>>2];
      dot  += acc[j]*xv.x + acc[j+1]*xv.y + acc[j+2]*xv.z + acc[j+3]*xv.w;
      dotu += u1p[j]*xv.x + u1p[j+1]*xv.y + u1p[j+2]*xv.z + u1p[j+3]*xv.w;
    }
    lval = 0.08838834764831843f * (dot + dotu + b0[y]);
    lo[(u64)y*N + row] = lval;
  }
  float e = (row < N) ? expf(lval) : 0.f;
#pragma unroll
  for (int o=32;o;o>>=1) e += __shfl_xor(e, o);
  if ((threadIdx.x & 63) == 0) atomicAdd(&Z[y], (double)e);
}

// ---------------- aggregation: one wave per dst node, lane-parallel softmax ----------------

__global__ __launch_bounds__(256) void k_agg(const int* __restrict__ off, const int* __restrict__ csr,
                                             const double* __restrict__ s, const float* __restrict__ v,
                                             const float* __restrict__ l, const double* __restrict__ Z,
                                             float* __restrict__ out, int N, int E){
  int gid = blockIdx.x*256 + threadIdx.x;
  int n = gid >> 6, lane = gid & 63;
  if (n >= N) return;
  int y = blockIdx.y;
  const int* offp = off + (u64)y*(N+1);
  const int* csrp = csr + (u64)y*E;
  const double* sp = s + (u64)(1-y)*N;       // logits live on src type = other type
  const float* vsrc = v + (u64)(1-y)*N*D;
  const float* vself = v + (u64)y*N*D;

  int beg = offp[n], end = offp[n+1];
  int deg = end - beg;
  float ax = 0.f, ay = 0.f;
  if (deg > 0){
    if (deg <= 64){
      bool act = lane < deg;
      int idx = csrp[beg + (act ? lane : 0)];
      double sv = sp[idx];
      if (!act) sv = -1e300;
      double m = sv;
#pragma unroll
      for (int o=32;o;o>>=1){ double t = __shfl_xor(m, o); m = t > m ? t : m; }
      float e = act ? expf((float)(sv - m)) : 0.f;
      float Zl = e;
#pragma unroll
      for (int o=32;o;o>>=1) Zl += __shfl_xor(Zl, o);
      float wgt = e / (Zl * (float)deg);
      for (int k=0;k<deg;++k){
        float wk = __shfl(wgt, k);
        int sk = __shfl(idx, k);
        float2 vv = ((const float2*)(vsrc + (u64)sk*D))[lane];
        ax = fmaf(wk, vv.x, ax);
        ay = fmaf(wk, vv.y, ay);
      }
    } else {
      // fallback (deg > 64): serial 3-pass, practically never taken
      double m = -1e300;
      for (int e=beg;e<end;++e){ double sv = sp[csrp[e]]; m = sv > m ? sv : m; }
      float Zl = 0.f;
      for (int e=beg;e<end;++e) Zl += expf((float)(sp[csrp[e]] - m));
      float inv = 1.f / (Zl * (float)deg);
      for (int e=beg;e<end;++e){
        int src = csrp[e];
        float w2 = expf((float)(sp[src] - m)) * inv;
        float2 vv = ((const float2*)(vsrc + (u64)src*D))[lane];
        ax = fmaf(w2, vv.x, ax);
        ay = fmaf(w2, vv.y, ay);
      }
    }
  }
  float a = expf(l[(u64)y*N + n]) / (float)(Z[y]);
  float2 vs = ((const float2*)(vself + (u64)n*D))[lane];
  ax = fmaf(a, vs.x, ax);
  ay = fmaf(a, vs.y, ay);
  ((float2*)(out + (u64)y*N*D + (u64)n*D))[lane] = make_float2(ax, ay);
}

// ---------------- launch ----------------

extern "C" void kernel_launch(void* const* d_in, const int* in_sizes, int n_in,
                              void* d_out, int out_size, void* d_ws, size_t ws_size,
                              hipStream_t stream){
  const float* x_user = (const float*)d_in[0];
  const float* x_item = (const float*)d_in[1];
  const int*   ei_u2i = (const int*)d_in[2];   // [2,E]: row0 src(user), row1 dst(item)
  const int*   ei_i2u = (const int*)d_in[3];   // [2,E]: row0 src(item), row1 dst(user)
  const float* qkv_w  = (const float*)d_in[4]; // [2,2,3,D,D]
  const float* qkv_b  = (const float*)d_in[5]; // [2,2,3,D]
  const float* rel_w  = (const float*)d_in[6]; // [2,2,D,D]
  const float* self_w = (const float*)d_in[7]; // [2,D,D]
  const float* self_b = (const float*)d_in[8]; // [2,D]

  const int N = in_sizes[0] / D;
  const int E = in_sizes[2] / 2;
  float* outU = (float*)d_out;                 // [2][N][D] contiguous (user then item)

  char* p = (char*)d_ws;
  auto alloc = [&](size_t bytes)->char*{ char* r = p; p += (bytes + 255)/256*256; return r; };
  float*  v    = (float*) alloc((u64)2*N*D*4);
  double* s    = (double*)alloc((u64)2*N*8);
  float*  l    = (float*) alloc((u64)2*N*4);
  int*    deg  = (int*)   alloc((u64)2*N*4);
  int*    off  = (int*)   alloc((u64)2*(N+1)*4);
  int*    cur  = (int*)   alloc((u64)2*N*4);
  int*    csr  = (int*)   alloc((u64)2*E*4);
  float*  M    = (float*) alloc((u64)2*D*D*4);
  float*  u1   = (float*) alloc(2*D*4);
  float*  b0   = (float*) alloc(256);
  char* zbase = p;                             // zero-init group (per layer)
  double* xsum = (double*)alloc(2*128*8);
  double* Z    = (double*)alloc(256);
  size_t zbytes = (size_t)(p - zbase);
  double* c    = (double*)alloc(2*128*8);
  double* c0   = (double*)alloc(256);

  const int gE = (E + 255)/256;
  const int gRow  = (N + 255)/256;
  const int gWave = (N + 3)/4;

  // ---- graph prep (layer-invariant): y=0 -> dst=user (ei_i2u), y=1 -> dst=item (ei_u2i)
  hipMemsetAsync(deg, 0, (u64)2*N*4, stream);
  k_hist<<<dim3(gE,2),256,0,stream>>>(ei_i2u + E, ei_u2i + E, deg, N, E);
  k_scan<<<dim3(1,2),1024,0,stream>>>(deg, off, cur, N);
  k_fill<<<dim3(gE,2),256,0,stream>>>(ei_i2u, ei_u2i, cur, csr, N, E);

  for (int L=0; L<2; ++L){
    const float* xu = L ? outU : x_user;
    const float* xi = L ? (outU + (u64)N*D) : x_item;
    hipMemsetAsync(zbase, 0, zbytes, stream);
    k_xsum<<<dim3(256,2),256,0,stream>>>(xu, xi, deg, xsum, N);
    k_coef<<<dim3(2,1),128,0,stream>>>(xsum, qkv_w, qkv_b, rel_w, L, E, c, c0);
    k_prepM<<<dim3(128,2),128,0,stream>>>(qkv_w, qkv_b, L, M, u1, b0);
    k_qz<<<dim3(gRow,2),256,0,stream>>>(xu, xi, M, u1, b0, l, Z, N);
    k_rowv<<<dim3(gRow,2),256,0,stream>>>(xu, xi, qkv_w, qkv_b, L, c, c0, v, s, N);
    k_agg<<<dim3(gWave,2),256,0,stream>>>(off, csr, s, v, l, Z, outU, N, E);
  }
  k_rowres<<<dim3(gRow,2),256,0,stream>>>(outU, self_w, self_b, N);
}

// Round 3
// 1496.256 us; speedup vs baseline: 2.1144x; 1.3597x over previous
//
#include <hip/hip_runtime.h>

#define D 128
typedef unsigned long long u64;

// ---------------- graph prep ----------------

__global__ __launch_bounds__(256) void k_hist(const int* __restrict__ dstA, const int* __restrict__ dstB,
                                              int* __restrict__ deg, int N, int E){
  int e = blockIdx.x*256 + threadIdx.x;
  int y = blockIdx.y;
  const int* d = y ? dstB : dstA;
  if (e < E) atomicAdd(&deg[(u64)y*N + d[e]], 1);
}

__global__ __launch_bounds__(1024) void k_scan(const int* __restrict__ degA, int* __restrict__ offA,
                                               int* __restrict__ curA, int n){
  int y = blockIdx.y;
  const int* deg = degA + (u64)y*n;
  int* off = offA + (u64)y*(n+1);
  int* cur = curA + (u64)y*n;
  __shared__ int wsum[16];
  __shared__ int carry_sh;
  int t = threadIdx.x, lane = t & 63, wid = t >> 6;
  if (t == 0) carry_sh = 0;
  __syncthreads();
  const int TILE = 4096;
  for (int base = 0; base < n; base += TILE){
    int idx = base + t*4;
    int v0 = (idx+0 < n)? deg[idx+0] : 0;
    int v1 = (idx+1 < n)? deg[idx+1] : 0;
    int v2 = (idx+2 < n)? deg[idx+2] : 0;
    int v3 = (idx+3 < n)? deg[idx+3] : 0;
    int tsum = v0+v1+v2+v3;
    int sc = tsum;                       // inclusive wave scan
    for (int o=1;o<64;o<<=1){ int u = __shfl_up(sc,o); if (lane>=o) sc += u; }
    if (lane == 63) wsum[wid] = sc;
    __syncthreads();
    if (wid == 0 && lane < 16){
      int ws = wsum[lane];
      int s2 = ws;
      for (int o=1;o<16;o<<=1){ int u = __shfl_up(s2,o); if (lane>=o) s2 += u; }
      wsum[lane] = s2 - ws;              // exclusive wave offsets
    }
    __syncthreads();
    int excl = carry_sh + wsum[wid] + sc - tsum;
    int run = excl;
    if (idx+0 < n){ off[idx+0]=run; cur[idx+0]=run; run+=v0; }
    if (idx+1 < n){ off[idx+1]=run; cur[idx+1]=run; run+=v1; }
    if (idx+2 < n){ off[idx+2]=run; cur[idx+2]=run; run+=v2; }
    if (idx+3 < n){ off[idx+3]=run; cur[idx+3]=run; run+=v3; }
    __syncthreads();
    if (t == 1023) carry_sh = excl + tsum;
    __syncthreads();
  }
  if (t == 0) off[n] = carry_sh;
}

__global__ __launch_bounds__(256) void k_fill(const int* __restrict__ eiA, const int* __restrict__ eiB,
                                              int* __restrict__ cur, int* __restrict__ csr, int N, int E){
  int e = blockIdx.x*256 + threadIdx.x;
  int y = blockIdx.y;
  const int* ei = y ? eiB : eiA;
  if (e < E){
    int p = atomicAdd(&cur[(u64)y*N + ei[E + e]], 1);
    csr[(u64)y*E + p] = ei[e];
  }
}

// ---------------- per-layer small math ----------------

__global__ __launch_bounds__(256) void k_xsum(const float* __restrict__ x0, const float* __restrict__ x1,
                                              const int* __restrict__ deg, double* __restrict__ xsum, int N){
  int y = blockIdx.y;
  const float* x = y ? x1 : x0;
  const int* dg = deg + (u64)y*N;
  double* xs = xsum + y*128;
  int j = threadIdx.x & 127;
  int sub = threadIdx.x >> 7;
  double a = 0.0;
  for (int n = blockIdx.x*2 + sub; n < N; n += gridDim.x*2){
    int d = dg[n];
    if (d) a += (double)d * (double)x[(u64)n*D + j];
  }
  atomicAdd(&xs[j], a);
}

__global__ __launch_bounds__(128) void k_coef(const double* __restrict__ xsum, const float* __restrict__ qkv_w,
                                              const float* __restrict__ qkv_b, const float* __restrict__ rel_w,
                                              int L, int E, double* __restrict__ c, double* __restrict__ c0){
  int t = blockIdx.x;       // src node type whose coefficients we compute
  const float* Wk = qkv_w + (u64)((L*2 + (1-t))*3 + 1)*D*D;
  const float* bk = qkv_b + (u64)((L*2 + (1-t))*3 + 1)*D;
  const float* Wq = qkv_w + (u64)((L*2 + t)*3 + 0)*D*D;
  const float* bq = qkv_b + (u64)((L*2 + t)*3 + 0)*D;
  const float* rel = rel_w + (u64)(L*2 + t)*D*D;
  const double* xs0 = xsum + (1-t)*128;

  __shared__ double sh[128];
  __shared__ double xs[128];
  int j = threadIdx.x;
  xs[j] = xs0[j];
  __syncthreads();
  double ks = (double)E * (double)bk[j];
  for (int d=0; d<128; ++d) ks += xs[d] * (double)Wk[d*128+j];
  sh[j] = ks;
  __syncthreads();
  double tmp = 0.0;
  for (int cc=0; cc<128; ++cc) tmp += (double)rel[j*128+cc] * sh[cc];
  __syncthreads();
  sh[j] = tmp;
  __syncthreads();
  const double scale = 0.08838834764831843;  // 1/sqrt(128)
  double cv = 0.0;
  for (int k2=0;k2<128;++k2) cv += (double)Wq[j*128+k2] * sh[k2];
  c[t*128 + j] = cv * scale;
  if (j == 0){
    double z = 0.0;
    for (int k2=0;k2<128;++k2) z += (double)bq[k2] * sh[k2];
    c0[t] = z * scale;
  }
}

__global__ __launch_bounds__(128) void k_prepM(const float* __restrict__ qkv_w, const float* __restrict__ qkv_b,
                                               int L, float* __restrict__ M, float* __restrict__ u1,
                                               float* __restrict__ b0){
  int y = blockIdx.y;
  const float* Wq = qkv_w + (u64)((L*2 + y)*3 + 0)*D*D;
  const float* Wk = qkv_w + (u64)((L*2 + y)*3 + 1)*D*D;
  const float* bq = qkv_b + (u64)((L*2 + y)*3 + 0)*D;
  const float* bk = qkv_b + (u64)((L*2 + y)*3 + 1)*D;
  int a = blockIdx.x, b = threadIdx.x;
  __shared__ float qrow[128];
  qrow[b] = Wq[a*128+b];
  __syncthreads();
  const float* krow = Wk + b*128;
  float acc = 0.f;
  for (int j=0;j<128;++j) acc += qrow[j]*krow[j];
  M[(u64)y*D*D + a*128 + b] = acc;
  if (b == 0){
    float s1 = 0.f;
    for (int j=0;j<128;++j) s1 += Wq[a*128+j]*bk[j] + Wk[a*128+j]*bq[j];
    u1[y*D + a] = s1;
    if (a == 0){
      float z = 0.f;
      for (int j=0;j<128;++j) z += bq[j]*bk[j];
      b0[y] = z;
    }
  }
}

// s[t][n] = x_t[n].c[t] + c0[t]  (f64), one wave per row
__global__ __launch_bounds__(256) void k_sdot(const float* __restrict__ x0, const float* __restrict__ x1,
                                              const double* __restrict__ c, const double* __restrict__ c0,
                                              double* __restrict__ s, int N){
  int gid = blockIdx.x*256 + threadIdx.x;
  int wv = gid >> 6, lane = gid & 63;
  if (wv >= N) return;
  int t = blockIdx.y;
  const float* x = t ? x1 : x0;
  const double* cc = c + t*128;
  const float* xr = x + (u64)wv*D;
  double p = (double)xr[lane]*cc[lane] + (double)xr[lane+64]*cc[lane+64];
#pragma unroll
  for (int o=32;o;o>>=1) p += __shfl_xor(p, o);
  if (lane == 0) s[(u64)t*N + wv] = p + c0[t];
}

// ---------------- LDS-tiled GEMM: 64 rows x 128 cols per block ----------------
// MODE 0: out = x@Wv + bv       (v projection)
// MODE 1: T = x@M; l = scale*(rowdot(T,x) + x.u1 + b0); zpart per block
// MODE 2: io = io@Wself + bself + io  (in-place residual)

__device__ __forceinline__ void chunk4(const float* __restrict__ Ws, int k0, int tc,
                                       const float4 xv[8], float acc[8][4]){
  const float* wr = Ws + k0*128 + tc*4;
  float4 w0 = *(const float4*)(wr);
  float4 w1 = *(const float4*)(wr + 128);
  float4 w2 = *(const float4*)(wr + 256);
  float4 w3 = *(const float4*)(wr + 384);
#pragma unroll
  for (int rr=0;rr<8;++rr){
    float4 xvv = xv[rr];
    acc[rr][0] = fmaf(xvv.w,w3.x, fmaf(xvv.z,w2.x, fmaf(xvv.y,w1.x, fmaf(xvv.x,w0.x, acc[rr][0]))));
    acc[rr][1] = fmaf(xvv.w,w3.y, fmaf(xvv.z,w2.y, fmaf(xvv.y,w1.y, fmaf(xvv.x,w0.y, acc[rr][1]))));
    acc[rr][2] = fmaf(xvv.w,w3.z, fmaf(xvv.z,w2.z, fmaf(xvv.y,w1.z, fmaf(xvv.x,w0.z, acc[rr][2]))));
    acc[rr][3] = fmaf(xvv.w,w3.w, fmaf(xvv.z,w2.w, fmaf(xvv.y,w1.w, fmaf(xvv.x,w0.w, acc[rr][3]))));
  }
}

template<int MODE>
__global__ __launch_bounds__(256, 2) void k_gemm(
    const float* __restrict__ x0, const float* __restrict__ x1,
    const float* __restrict__ qkv_w, const float* __restrict__ qkv_b,
    const float* __restrict__ M, const float* __restrict__ u1, const float* __restrict__ b0,
    const float* __restrict__ self_w, const float* __restrict__ self_b,
    float* __restrict__ vout, float* __restrict__ lo, double* __restrict__ zpart,
    float* __restrict__ io, int L, int N)
{
  __shared__ float4 Ws4[4096];               // 64 KB: W[k][j] linear f32
  float* Ws = (float*)Ws4;
  int y = blockIdx.y;
  int t = threadIdx.x;

  const float* x = nullptr; const float* W = nullptr; const float* bias = nullptr; float* out = nullptr;
  if (MODE == 0){
    x = y ? x1 : x0;
    W = qkv_w + (u64)((L*2 + y)*3 + 2)*D*D;
    bias = qkv_b + (u64)((L*2 + y)*3 + 2)*D;
    out = vout + (u64)y*N*D;
  } else if (MODE == 1){
    x = y ? x1 : x0;
    W = M + (u64)y*D*D;
  } else {
    x = io + (u64)y*N*D;
    W = self_w + (u64)y*D*D;
    bias = self_b + y*D;
    out = io + (u64)y*N*D;
  }

  {
    const float4* Wv = (const float4*)W;
#pragma unroll
    for (int i=0;i<16;++i) Ws4[t + i*256] = Wv[t + i*256];
  }
  __syncthreads();

  int tc = t & 31, tr = t >> 5;
  int row0 = blockIdx.x*64 + tr*8;

  const float4* xr[8];
#pragma unroll
  for (int rr=0;rr<8;++rr){
    int r = row0 + rr; if (r > N-1) r = N-1;
    xr[rr] = (const float4*)(x + (u64)r*D);
  }

  float acc[8][4];
#pragma unroll
  for (int rr=0;rr<8;++rr){ acc[rr][0]=0.f; acc[rr][1]=0.f; acc[rr][2]=0.f; acc[rr][3]=0.f; }

  float4 xv0[8], xv1[8];
#pragma unroll
  for (int rr=0;rr<8;++rr) xv0[rr] = xr[rr][0];
  for (int k0=0; k0<128; k0+=8){
#pragma unroll
    for (int rr=0;rr<8;++rr) xv1[rr] = xr[rr][(k0>>2)+1];
    chunk4(Ws, k0, tc, xv0, acc);
    if (k0 + 8 < 128){
#pragma unroll
      for (int rr=0;rr<8;++rr) xv0[rr] = xr[rr][(k0>>2)+2];
    }
    chunk4(Ws, k0+4, tc, xv1, acc);
  }

  if (MODE == 0){
    float4 bv = ((const float4*)bias)[tc];
#pragma unroll
    for (int rr=0;rr<8;++rr){
      int row = row0 + rr;
      if (row < N){
        float4 o = make_float4(acc[rr][0]+bv.x, acc[rr][1]+bv.y, acc[rr][2]+bv.z, acc[rr][3]+bv.w);
        ((float4*)(out + (u64)row*D))[tc] = o;
      }
    }
  } else if (MODE == 1){
    float4 uv = ((const float4*)(u1 + y*D))[tc];
    float dsum[8];
#pragma unroll
    for (int rr=0;rr<8;++rr){
      float4 xvv = xr[rr][tc];
      dsum[rr] = acc[rr][0]*xvv.x + acc[rr][1]*xvv.y + acc[rr][2]*xvv.z + acc[rr][3]*xvv.w
               + uv.x*xvv.x + uv.y*xvv.y + uv.z*xvv.z + uv.w*xvv.w;
    }
#pragma unroll
    for (int o=16;o;o>>=1){
#pragma unroll
      for (int rr=0;rr<8;++rr) dsum[rr] += __shfl_xor(dsum[rr], o);
    }
    double esum = 0.0;
    if (tc == 0){
      float b0v = b0[y];
#pragma unroll
      for (int rr=0;rr<8;++rr){
        int row = row0 + rr;
        if (row < N){
          float lval = 0.08838834764831843f * (dsum[rr] + b0v);
          lo[(u64)y*N + row] = lval;
          esum += (double)expf(lval);
        }
      }
    }
    __syncthreads();                       // Ws reads done; reuse LDS for z reduce
    double* zsh = (double*)Ws;
    if (tc == 0) zsh[tr] = esum;
    __syncthreads();
    if (t == 0){
      double zt = 0.0;
#pragma unroll
      for (int i=0;i<8;++i) zt += zsh[i];
      zpart[(u64)y*gridDim.x + blockIdx.x] = zt;
    }
  } else {
    float4 bv = ((const float4*)bias)[tc];
    float4 xres[8];
#pragma unroll
    for (int rr=0;rr<8;++rr) xres[rr] = xr[rr][tc];
    __syncthreads();                       // all tile reads complete before in-place stores
#pragma unroll
    for (int rr=0;rr<8;++rr){
      int row = row0 + rr;
      if (row < N){
        float4 o = make_float4(acc[rr][0]+bv.x+xres[rr].x, acc[rr][1]+bv.y+xres[rr].y,
                               acc[rr][2]+bv.z+xres[rr].z, acc[rr][3]+bv.w+xres[rr].w);
        ((float4*)(out + (u64)row*D))[tc] = o;
      }
    }
  }
}

__global__ __launch_bounds__(256) void k_zred(const double* __restrict__ zpart, double* __restrict__ Z, int nblk){
  int y = blockIdx.x;
  double a = 0.0;
  for (int i=threadIdx.x; i<nblk; i+=256) a += zpart[(u64)y*nblk + i];
#pragma unroll
  for (int o=32;o;o>>=1) a += __shfl_xor(a, o);
  __shared__ double sh[4];
  if ((threadIdx.x & 63) == 0) sh[threadIdx.x>>6] = a;
  __syncthreads();
  if (threadIdx.x == 0) Z[y] = sh[0]+sh[1]+sh[2]+sh[3];
}

// ---------------- aggregation: one wave per dst node, lane-parallel softmax ----------------

__global__ __launch_bounds__(256) void k_agg(const int* __restrict__ off, const int* __restrict__ csr,
                                             const double* __restrict__ s, const float* __restrict__ v,
                                             const float* __restrict__ l, const double* __restrict__ Z,
                                             float* __restrict__ out, int N, int E){
  int gid = blockIdx.x*256 + threadIdx.x;
  int n = gid >> 6, lane = gid & 63;
  if (n >= N) return;
  int y = blockIdx.y;
  const int* offp = off + (u64)y*(N+1);
  const int* csrp = csr + (u64)y*E;
  const double* sp = s + (u64)(1-y)*N;       // logits live on src type = other type
  const float* vsrc = v + (u64)(1-y)*N*D;
  const float* vself = v + (u64)y*N*D;

  int beg = offp[n], end = offp[n+1];
  int deg = end - beg;
  float ax = 0.f, ay = 0.f;
  if (deg > 0){
    if (deg <= 64){
      bool act = lane < deg;
      int idx = csrp[beg + (act ? lane : 0)];
      double sv = sp[idx];
      if (!act) sv = -1e300;
      double m = sv;
#pragma unroll
      for (int o=32;o;o>>=1){ double t = __shfl_xor(m, o); m = t > m ? t : m; }
      float e = act ? expf((float)(sv - m)) : 0.f;
      float Zl = e;
#pragma unroll
      for (int o=32;o;o>>=1) Zl += __shfl_xor(Zl, o);
      float wgt = e / (Zl * (float)deg);
      for (int k=0;k<deg;++k){
        float wk = __shfl(wgt, k);
        int sk = __shfl(idx, k);
        float2 vv = ((const float2*)(vsrc + (u64)sk*D))[lane];
        ax = fmaf(wk, vv.x, ax);
        ay = fmaf(wk, vv.y, ay);
      }
    } else {
      double m = -1e300;
      for (int e=beg;e<end;++e){ double sv = sp[csrp[e]]; m = sv > m ? sv : m; }
      float Zl = 0.f;
      for (int e=beg;e<end;++e) Zl += expf((float)(sp[csrp[e]] - m));
      float inv = 1.f / (Zl * (float)deg);
      for (int e=beg;e<end;++e){
        int src = csrp[e];
        float w2 = expf((float)(sp[src] - m)) * inv;
        float2 vv = ((const float2*)(vsrc + (u64)src*D))[lane];
        ax = fmaf(w2, vv.x, ax);
        ay = fmaf(w2, vv.y, ay);
      }
    }
  }
  float a = expf(l[(u64)y*N + n]) / (float)(Z[y]);
  float2 vs = ((const float2*)(vself + (u64)n*D))[lane];
  ax = fmaf(a, vs.x, ax);
  ay = fmaf(a, vs.y, ay);
  ((float2*)(out + (u64)y*N*D + (u64)n*D))[lane] = make_float2(ax, ay);
}

// ---------------- launch ----------------

extern "C" void kernel_launch(void* const* d_in, const int* in_sizes, int n_in,
                              void* d_out, int out_size, void* d_ws, size_t ws_size,
                              hipStream_t stream){
  const float* x_user = (const float*)d_in[0];
  const float* x_item = (const float*)d_in[1];
  const int*   ei_u2i = (const int*)d_in[2];   // [2,E]: row0 src(user), row1 dst(item)
  const int*   ei_i2u = (const int*)d_in[3];   // [2,E]: row0 src(item), row1 dst(user)
  const float* qkv_w  = (const float*)d_in[4]; // [2,2,3,D,D]
  const float* qkv_b  = (const float*)d_in[5]; // [2,2,3,D]
  const float* rel_w  = (const float*)d_in[6]; // [2,2,D,D]
  const float* self_w = (const float*)d_in[7]; // [2,D,D]
  const float* self_b = (const float*)d_in[8]; // [2,D]

  const int N = in_sizes[0] / D;
  const int E = in_sizes[2] / 2;
  float* outU = (float*)d_out;                 // [2][N][D] contiguous (user then item)

  const int nblk = (N + 63)/64;

  char* p = (char*)d_ws;
  auto alloc = [&](size_t bytes)->char*{ char* r = p; p += (bytes + 255)/256*256; return r; };
  float*  v    = (float*) alloc((u64)2*N*D*4);
  double* s    = (double*)alloc((u64)2*N*8);
  float*  l    = (float*) alloc((u64)2*N*4);
  int*    deg  = (int*)   alloc((u64)2*N*4);
  int*    off  = (int*)   alloc((u64)2*(N+1)*4);
  int*    cur  = (int*)   alloc((u64)2*N*4);
  int*    csr  = (int*)   alloc((u64)2*E*4);
  float*  M    = (float*) alloc((u64)2*D*D*4);
  float*  u1   = (float*) alloc(2*D*4);
  float*  b0   = (float*) alloc(256);
  double* zpart= (double*)alloc((u64)2*nblk*8);
  double* Z    = (double*)alloc(256);
  double* xsum = (double*)alloc(2*128*8);
  double* c    = (double*)alloc(2*128*8);
  double* c0   = (double*)alloc(256);

  const int gE = (E + 255)/256;
  const int gWave = (N + 3)/4;

  // ---- graph prep (layer-invariant): y=0 -> dst=user (ei_i2u), y=1 -> dst=item (ei_u2i)
  hipMemsetAsync(deg, 0, (u64)2*N*4, stream);
  k_hist<<<dim3(gE,2),256,0,stream>>>(ei_i2u + E, ei_u2i + E, deg, N, E);
  k_scan<<<dim3(1,2),1024,0,stream>>>(deg, off, cur, N);
  k_fill<<<dim3(gE,2),256,0,stream>>>(ei_i2u, ei_u2i, cur, csr, N, E);

  for (int L=0; L<2; ++L){
    const float* xu = L ? outU : x_user;
    const float* xi = L ? (outU + (u64)N*D) : x_item;
    hipMemsetAsync(xsum, 0, 2*128*8, stream);
    k_xsum<<<dim3(256,2),256,0,stream>>>(xu, xi, deg, xsum, N);
    k_coef<<<dim3(2,1),128,0,stream>>>(xsum, qkv_w, qkv_b, rel_w, L, E, c, c0);
    k_prepM<<<dim3(128,2),128,0,stream>>>(qkv_w, qkv_b, L, M, u1, b0);
    k_gemm<1><<<dim3(nblk,2),256,0,stream>>>(xu, xi, qkv_w, qkv_b, M, u1, b0, self_w, self_b,
                                             v, l, zpart, outU, L, N);
    k_zred<<<2,256,0,stream>>>(zpart, Z, nblk);
    k_sdot<<<dim3(gWave,2),256,0,stream>>>(xu, xi, c, c0, s, N);
    k_gemm<0><<<dim3(nblk,2),256,0,stream>>>(xu, xi, qkv_w, qkv_b, M, u1, b0, self_w, self_b,
                                             v, l, zpart, outU, L, N);
    k_agg<<<dim3(gWave,2),256,0,stream>>>(off, csr, s, v, l, Z, outU, N, E);
  }
  k_gemm<2><<<dim3(nblk,2),256,0,stream>>>(nullptr, nullptr, qkv_w, qkv_b, M, u1, b0, self_w, self_b,
                                           v, l, zpart, outU, 0, N);
}

// Round 4
// 1304.632 us; speedup vs baseline: 2.4250x; 1.1469x over previous
//
#include <hip/hip_runtime.h>

#define D 128
typedef unsigned long long u64;

// ---------------- graph prep ----------------

__global__ __launch_bounds__(256) void k_hist(const int* __restrict__ dstA, const int* __restrict__ dstB,
                                              int* __restrict__ deg, int N, int E){
  int e = blockIdx.x*256 + threadIdx.x;
  int y = blockIdx.y;
  const int* d = y ? dstB : dstA;
  if (e < E) atomicAdd(&deg[(u64)y*N + d[e]], 1);
}

__global__ __launch_bounds__(1024) void k_scan(const int* __restrict__ degA, int* __restrict__ offA,
                                               int* __restrict__ curA, int n){
  int y = blockIdx.y;
  const int* deg = degA + (u64)y*n;
  int* off = offA + (u64)y*(n+1);
  int* cur = curA + (u64)y*n;
  __shared__ int wsum[16];
  __shared__ int carry_sh;
  int t = threadIdx.x, lane = t & 63, wid = t >> 6;
  if (t == 0) carry_sh = 0;
  __syncthreads();
  const int TILE = 4096;
  for (int base = 0; base < n; base += TILE){
    int idx = base + t*4;
    int v0 = (idx+0 < n)? deg[idx+0] : 0;
    int v1 = (idx+1 < n)? deg[idx+1] : 0;
    int v2 = (idx+2 < n)? deg[idx+2] : 0;
    int v3 = (idx+3 < n)? deg[idx+3] : 0;
    int tsum = v0+v1+v2+v3;
    int sc = tsum;                       // inclusive wave scan
    for (int o=1;o<64;o<<=1){ int u = __shfl_up(sc,o); if (lane>=o) sc += u; }
    if (lane == 63) wsum[wid] = sc;
    __syncthreads();
    if (wid == 0 && lane < 16){
      int ws = wsum[lane];
      int s2 = ws;
      for (int o=1;o<16;o<<=1){ int u = __shfl_up(s2,o); if (lane>=o) s2 += u; }
      wsum[lane] = s2 - ws;              // exclusive wave offsets
    }
    __syncthreads();
    int excl = carry_sh + wsum[wid] + sc - tsum;
    int run = excl;
    if (idx+0 < n){ off[idx+0]=run; cur[idx+0]=run; run+=v0; }
    if (idx+1 < n){ off[idx+1]=run; cur[idx+1]=run; run+=v1; }
    if (idx+2 < n){ off[idx+2]=run; cur[idx+2]=run; run+=v2; }
    if (idx+3 < n){ off[idx+3]=run; cur[idx+3]=run; run+=v3; }
    __syncthreads();
    if (t == 1023) carry_sh = excl + tsum;
    __syncthreads();
  }
  if (t == 0) off[n] = carry_sh;
}

__global__ __launch_bounds__(256) void k_fill(const int* __restrict__ eiA, const int* __restrict__ eiB,
                                              int* __restrict__ cur, int* __restrict__ csr, int N, int E){
  int e = blockIdx.x*256 + threadIdx.x;
  int y = blockIdx.y;
  const int* ei = y ? eiB : eiA;
  if (e < E){
    int p = atomicAdd(&cur[(u64)y*N + ei[E + e]], 1);
    csr[(u64)y*E + p] = ei[e];
  }
}

// ---------------- per-layer small math ----------------

__global__ __launch_bounds__(128) void k_coef(const double* __restrict__ xsum, const float* __restrict__ qkv_w,
                                              const float* __restrict__ qkv_b, const float* __restrict__ rel_w,
                                              int L, int E, double* __restrict__ c, double* __restrict__ c0){
  int t = blockIdx.x;       // src node type whose coefficients we compute
  const float* Wk = qkv_w + (u64)((L*2 + (1-t))*3 + 1)*D*D;
  const float* bk = qkv_b + (u64)((L*2 + (1-t))*3 + 1)*D;
  const float* Wq = qkv_w + (u64)((L*2 + t)*3 + 0)*D*D;
  const float* bq = qkv_b + (u64)((L*2 + t)*3 + 0)*D;
  const float* rel = rel_w + (u64)(L*2 + t)*D*D;
  const double* xs0 = xsum + (1-t)*128;

  __shared__ double sh[128];
  __shared__ double xs[128];
  int j = threadIdx.x;
  xs[j] = xs0[j];
  __syncthreads();
  double ks = (double)E * (double)bk[j];
  for (int d=0; d<128; ++d) ks += xs[d] * (double)Wk[d*128+j];
  sh[j] = ks;
  __syncthreads();
  double tmp = 0.0;
  for (int cc=0; cc<128; ++cc) tmp += (double)rel[j*128+cc] * sh[cc];
  __syncthreads();
  sh[j] = tmp;
  __syncthreads();
  const double scale = 0.08838834764831843;  // 1/sqrt(128)
  double cv = 0.0;
  for (int k2=0;k2<128;++k2) cv += (double)Wq[j*128+k2] * sh[k2];
  c[t*128 + j] = cv * scale;
  if (j == 0){
    double z = 0.0;
    for (int k2=0;k2<128;++k2) z += (double)bq[k2] * sh[k2];
    c0[t] = z * scale;
  }
}

__global__ __launch_bounds__(128) void k_prepM(const float* __restrict__ qkv_w, const float* __restrict__ qkv_b,
                                               int L, float* __restrict__ M, float* __restrict__ u1,
                                               float* __restrict__ b0){
  int y = blockIdx.y;
  const float* Wq = qkv_w + (u64)((L*2 + y)*3 + 0)*D*D;
  const float* Wk = qkv_w + (u64)((L*2 + y)*3 + 1)*D*D;
  const float* bq = qkv_b + (u64)((L*2 + y)*3 + 0)*D;
  const float* bk = qkv_b + (u64)((L*2 + y)*3 + 1)*D;
  int a = blockIdx.x, b = threadIdx.x;
  __shared__ float qrow[128];
  qrow[b] = Wq[a*128+b];
  __syncthreads();
  const float* krow = Wk + b*128;
  float acc = 0.f;
  for (int j=0;j<128;++j) acc += qrow[j]*krow[j];
  M[(u64)y*D*D + a*128 + b] = acc;
  if (b == 0){
    float s1 = 0.f;
    for (int j=0;j<128;++j) s1 += Wq[a*128+j]*bk[j] + Wk[a*128+j]*bq[j];
    u1[y*D + a] = s1;
    if (a == 0){
      float z = 0.f;
      for (int j=0;j<128;++j) z += bq[j]*bk[j];
      b0[y] = z;
    }
  }
}

// ---------------- LDS-tiled GEMM: 64 rows x 128 cols per block ----------------
// MODE 0: out = x@Wv + bv ; s[row] = x[row].c + c0 (f64, fused sdot)
// MODE 1: T = x@M; l = scale*(rowdot(T,x) + x.u1 + b0); zpart + xsum-partials per block
// MODE 2: io = io@Wself + bself + io  (in-place residual)

__device__ __forceinline__ void chunk4(const float* __restrict__ Ws, int k0, int tc,
                                       const float4 xv[8], float acc[8][4]){
  const float* wr = Ws + k0*128 + tc*4;
  float4 w0 = *(const float4*)(wr);
  float4 w1 = *(const float4*)(wr + 128);
  float4 w2 = *(const float4*)(wr + 256);
  float4 w3 = *(const float4*)(wr + 384);
#pragma unroll
  for (int rr=0;rr<8;++rr){
    float4 xvv = xv[rr];
    acc[rr][0] = fmaf(xvv.w,w3.x, fmaf(xvv.z,w2.x, fmaf(xvv.y,w1.x, fmaf(xvv.x,w0.x, acc[rr][0]))));
    acc[rr][1] = fmaf(xvv.w,w3.y, fmaf(xvv.z,w2.y, fmaf(xvv.y,w1.y, fmaf(xvv.x,w0.y, acc[rr][1]))));
    acc[rr][2] = fmaf(xvv.w,w3.z, fmaf(xvv.z,w2.z, fmaf(xvv.y,w1.z, fmaf(xvv.x,w0.z, acc[rr][2]))));
    acc[rr][3] = fmaf(xvv.w,w3.w, fmaf(xvv.z,w2.w, fmaf(xvv.y,w1.w, fmaf(xvv.x,w0.w, acc[rr][3]))));
  }
}

template<int MODE>
__global__ __launch_bounds__(256, 2) void k_gemm(
    const float* __restrict__ x0, const float* __restrict__ x1,
    const float* __restrict__ qkv_w, const float* __restrict__ qkv_b,
    const float* __restrict__ M, const float* __restrict__ u1, const float* __restrict__ b0,
    const float* __restrict__ self_w, const float* __restrict__ self_b,
    const int* __restrict__ deg, const double* __restrict__ c, const double* __restrict__ c0,
    float* __restrict__ vout, float* __restrict__ lo,
    double* __restrict__ zpart, double* __restrict__ xpart, double* __restrict__ s,
    float* __restrict__ io, int L, int N)
{
  __shared__ float4 Ws4[4096];               // 64 KB: W[k][j] linear f32
  __shared__ double csh[128];
  float* Ws = (float*)Ws4;
  int y = blockIdx.y;
  int t = threadIdx.x;

  const float* x = nullptr; const float* W = nullptr; const float* bias = nullptr; float* out = nullptr;
  if (MODE == 0){
    x = y ? x1 : x0;
    W = qkv_w + (u64)((L*2 + y)*3 + 2)*D*D;
    bias = qkv_b + (u64)((L*2 + y)*3 + 2)*D;
    out = vout + (u64)y*N*D;
  } else if (MODE == 1){
    x = y ? x1 : x0;
    W = M + (u64)y*D*D;
  } else {
    x = io + (u64)y*N*D;
    W = self_w + (u64)y*D*D;
    bias = self_b + y*D;
    out = io + (u64)y*N*D;
  }

  {
    const float4* Wv = (const float4*)W;
#pragma unroll
    for (int i=0;i<16;++i) Ws4[t + i*256] = Wv[t + i*256];
    if (MODE == 0 && t < 128) csh[t] = c[y*128 + t];
  }
  __syncthreads();

  int tc = t & 31, tr = t >> 5;
  int row0 = blockIdx.x*64 + tr*8;

  const float4* xr[8];
#pragma unroll
  for (int rr=0;rr<8;++rr){
    int r = row0 + rr; if (r > N-1) r = N-1;
    xr[rr] = (const float4*)(x + (u64)r*D);
  }

  float acc[8][4];
#pragma unroll
  for (int rr=0;rr<8;++rr){ acc[rr][0]=0.f; acc[rr][1]=0.f; acc[rr][2]=0.f; acc[rr][3]=0.f; }
  double sacc[8];
  if (MODE == 0){
#pragma unroll
    for (int rr=0;rr<8;++rr) sacc[rr] = 0.0;
  }

  float4 xv0[8], xv1[8];
#pragma unroll
  for (int rr=0;rr<8;++rr) xv0[rr] = xr[rr][0];
  for (int k0=0; k0<128; k0+=8){
#pragma unroll
    for (int rr=0;rr<8;++rr) xv1[rr] = xr[rr][(k0>>2)+1];
    chunk4(Ws, k0, tc, xv0, acc);
    if (MODE == 0){
      double c0d = csh[k0], c1d = csh[k0+1], c2d = csh[k0+2], c3d = csh[k0+3];
#pragma unroll
      for (int rr=0;rr<8;++rr){
        float4 xvv = xv0[rr];
        sacc[rr] += (double)xvv.x*c0d + (double)xvv.y*c1d + (double)xvv.z*c2d + (double)xvv.w*c3d;
      }
    }
    if (k0 + 8 < 128){
#pragma unroll
      for (int rr=0;rr<8;++rr) xv0[rr] = xr[rr][(k0>>2)+2];
    }
    chunk4(Ws, k0+4, tc, xv1, acc);
    if (MODE == 0){
      double c0d = csh[k0+4], c1d = csh[k0+5], c2d = csh[k0+6], c3d = csh[k0+7];
#pragma unroll
      for (int rr=0;rr<8;++rr){
        float4 xvv = xv1[rr];
        sacc[rr] += (double)xvv.x*c0d + (double)xvv.y*c1d + (double)xvv.z*c2d + (double)xvv.w*c3d;
      }
    }
  }

  if (MODE == 0){
    float4 bv = ((const float4*)bias)[tc];
#pragma unroll
    for (int rr=0;rr<8;++rr){
      int row = row0 + rr;
      if (row < N){
        float4 o = make_float4(acc[rr][0]+bv.x, acc[rr][1]+bv.y, acc[rr][2]+bv.z, acc[rr][3]+bv.w);
        ((float4*)(out + (u64)row*D))[tc] = o;
      }
    }
    if (tc == 0){
      double cc0 = c0[y];
#pragma unroll
      for (int rr=0;rr<8;++rr){
        int row = row0 + rr;
        if (row < N) s[(u64)y*N + row] = sacc[rr] + cc0;
      }
    }
  } else if (MODE == 1){
    float4 uv = ((const float4*)(u1 + y*D))[tc];
    const int* dg = deg + (u64)y*N;
    float4 xcol[8];
    float dsum[8];
#pragma unroll
    for (int rr=0;rr<8;++rr){
      xcol[rr] = xr[rr][tc];
      dsum[rr] = acc[rr][0]*xcol[rr].x + acc[rr][1]*xcol[rr].y + acc[rr][2]*xcol[rr].z + acc[rr][3]*xcol[rr].w
               + uv.x*xcol[rr].x + uv.y*xcol[rr].y + uv.z*xcol[rr].z + uv.w*xcol[rr].w;
    }
#pragma unroll
    for (int o=16;o;o>>=1){
#pragma unroll
      for (int rr=0;rr<8;++rr) dsum[rr] += __shfl_xor(dsum[rr], o);
    }
    // xsum partial: sum_r deg[row]*x[row][4tc..4tc+3]  (f64)
    double a0=0.0, a1=0.0, a2=0.0, a3=0.0;
#pragma unroll
    for (int rr=0;rr<8;++rr){
      int row = row0 + rr;
      int dv = (row < N) ? dg[row] : 0;
      if (dv){
        double dd = (double)dv;
        a0 += dd*(double)xcol[rr].x; a1 += dd*(double)xcol[rr].y;
        a2 += dd*(double)xcol[rr].z; a3 += dd*(double)xcol[rr].w;
      }
    }
    double esum = 0.0;
    if (tc == 0){
      float b0v = b0[y];
#pragma unroll
      for (int rr=0;rr<8;++rr){
        int row = row0 + rr;
        if (row < N){
          float lval = 0.08838834764831843f * (dsum[rr] + b0v);
          lo[(u64)y*N + row] = lval;
          esum += (double)expf(lval);
        }
      }
    }
    __syncthreads();                       // all Ws tile reads done; reuse LDS for reductions
    double* dsh = (double*)Ws;
    dsh[tr*128 + 4*tc + 0] = a0;
    dsh[tr*128 + 4*tc + 1] = a1;
    dsh[tr*128 + 4*tc + 2] = a2;
    dsh[tr*128 + 4*tc + 3] = a3;
    if (tc == 0) dsh[1024 + tr] = esum;
    __syncthreads();
    if (t < 128){
      double ssum = 0.0;
#pragma unroll
      for (int r=0;r<8;++r) ssum += dsh[r*128 + t];
      xpart[((u64)y*gridDim.x + blockIdx.x)*128 + t] = ssum;
    }
    if (t == 0){
      double zt = 0.0;
#pragma unroll
      for (int r=0;r<8;++r) zt += dsh[1024 + r];
      zpart[(u64)y*gridDim.x + blockIdx.x] = zt;
    }
  } else {
    float4 bv = ((const float4*)bias)[tc];
    float4 xres[8];
#pragma unroll
    for (int rr=0;rr<8;++rr) xres[rr] = xr[rr][tc];
    __syncthreads();                       // all tile reads complete before in-place stores
#pragma unroll
    for (int rr=0;rr<8;++rr){
      int row = row0 + rr;
      if (row < N){
        float4 o = make_float4(acc[rr][0]+bv.x+xres[rr].x, acc[rr][1]+bv.y+xres[rr].y,
                               acc[rr][2]+bv.z+xres[rr].z, acc[rr][3]+bv.w+xres[rr].w);
        ((float4*)(out + (u64)row*D))[tc] = o;
      }
    }
  }
}

// ---- reduce xsum partials + Z : grid (8 slices, 2 types), 256 threads ----
__global__ __launch_bounds__(256) void k_red(const double* __restrict__ xpart, const double* __restrict__ zpart,
                                             double* __restrict__ xsum, double* __restrict__ Z, int nblk){
  int y = blockIdx.y, slice = blockIdx.x;
  int col = threadIdx.x & 127, half = threadIdx.x >> 7;
  double a = 0.0;
  for (int b = slice*2 + half; b < nblk; b += 16)
    a += xpart[((u64)y*nblk + b)*128 + col];
  __shared__ double sh[256];
  sh[threadIdx.x] = a;
  __syncthreads();
  if (half == 0) atomicAdd(&xsum[y*128 + col], a + sh[col + 128]);
  if (slice == 0){
    double z = 0.0;
    for (int i = threadIdx.x; i < nblk; i += 256) z += zpart[(u64)y*nblk + i];
#pragma unroll
    for (int o=32;o;o>>=1) z += __shfl_xor(z, o);
    __shared__ double zsh[4];
    if ((threadIdx.x & 63) == 0) zsh[threadIdx.x >> 6] = z;
    __syncthreads();
    if (threadIdx.x == 0) Z[y] = zsh[0]+zsh[1]+zsh[2]+zsh[3];
  }
}

// ---------------- aggregation: one wave per dst node, lane-parallel softmax ----------------

__global__ __launch_bounds__(256) void k_agg(const int* __restrict__ off, const int* __restrict__ csr,
                                             const double* __restrict__ s, const float* __restrict__ v,
                                             const float* __restrict__ l, const double* __restrict__ Z,
                                             float* __restrict__ out, int N, int E){
  int gid = blockIdx.x*256 + threadIdx.x;
  int n = gid >> 6, lane = gid & 63;
  if (n >= N) return;
  int y = blockIdx.y;
  const int* offp = off + (u64)y*(N+1);
  const int* csrp = csr + (u64)y*E;
  const double* sp = s + (u64)(1-y)*N;       // logits live on src type = other type
  const float* vsrc = v + (u64)(1-y)*N*D;
  const float* vself = v + (u64)y*N*D;

  int beg = offp[n], end = offp[n+1];
  int deg = end - beg;
  float ax = 0.f, ay = 0.f;
  if (deg > 0){
    if (deg <= 64){
      bool act = lane < deg;
      int idx = csrp[beg + (act ? lane : 0)];
      double sv = sp[idx];
      if (!act) sv = -1e300;
      double m = sv;
#pragma unroll
      for (int o=32;o;o>>=1){ double t = __shfl_xor(m, o); m = t > m ? t : m; }
      float e = act ? expf((float)(sv - m)) : 0.f;
      float Zl = e;
#pragma unroll
      for (int o=32;o;o>>=1) Zl += __shfl_xor(Zl, o);
      float wgt = e / (Zl * (float)deg);
      for (int k=0;k<deg;++k){
        float wk = __shfl(wgt, k);
        int sk = __shfl(idx, k);
        float2 vv = ((const float2*)(vsrc + (u64)sk*D))[lane];
        ax = fmaf(wk, vv.x, ax);
        ay = fmaf(wk, vv.y, ay);
      }
    } else {
      double m = -1e300;
      for (int e=beg;e<end;++e){ double sv = sp[csrp[e]]; m = sv > m ? sv : m; }
      float Zl = 0.f;
      for (int e=beg;e<end;++e) Zl += expf((float)(sp[csrp[e]] - m));
      float inv = 1.f / (Zl * (float)deg);
      for (int e=beg;e<end;++e){
        int src = csrp[e];
        float w2 = expf((float)(sp[src] - m)) * inv;
        float2 vv = ((const float2*)(vsrc + (u64)src*D))[lane];
        ax = fmaf(w2, vv.x, ax);
        ay = fmaf(w2, vv.y, ay);
      }
    }
  }
  float a = expf(l[(u64)y*N + n]) / (float)(Z[y]);
  float2 vs = ((const float2*)(vself + (u64)n*D))[lane];
  ax = fmaf(a, vs.x, ax);
  ay = fmaf(a, vs.y, ay);
  ((float2*)(out + (u64)y*N*D + (u64)n*D))[lane] = make_float2(ax, ay);
}

// ---------------- launch ----------------

extern "C" void kernel_launch(void* const* d_in, const int* in_sizes, int n_in,
                              void* d_out, int out_size, void* d_ws, size_t ws_size,
                              hipStream_t stream){
  const float* x_user = (const float*)d_in[0];
  const float* x_item = (const float*)d_in[1];
  const int*   ei_u2i = (const int*)d_in[2];   // [2,E]: row0 src(user), row1 dst(item)
  const int*   ei_i2u = (const int*)d_in[3];   // [2,E]: row0 src(item), row1 dst(user)
  const float* qkv_w  = (const float*)d_in[4]; // [2,2,3,D,D]
  const float* qkv_b  = (const float*)d_in[5]; // [2,2,3,D]
  const float* rel_w  = (const float*)d_in[6]; // [2,2,D,D]
  const float* self_w = (const float*)d_in[7]; // [2,D,D]
  const float* self_b = (const float*)d_in[8]; // [2,D]

  const int N = in_sizes[0] / D;
  const int E = in_sizes[2] / 2;
  float* outU = (float*)d_out;                 // [2][N][D] contiguous (user then item)

  const int nblk = (N + 63)/64;

  char* p = (char*)d_ws;
  auto alloc = [&](size_t bytes)->char*{ char* r = p; p += (bytes + 255)/256*256; return r; };
  float*  v    = (float*) alloc((u64)2*N*D*4);
  double* s    = (double*)alloc((u64)2*N*8);
  float*  l    = (float*) alloc((u64)2*N*4);
  int*    deg  = (int*)   alloc((u64)2*N*4);
  int*    off  = (int*)   alloc((u64)2*(N+1)*4);
  int*    cur  = (int*)   alloc((u64)2*N*4);
  int*    csr  = (int*)   alloc((u64)2*E*4);
  float*  M    = (float*) alloc((u64)2*D*D*4);
  float*  u1   = (float*) alloc(2*D*4);
  float*  b0   = (float*) alloc(256);
  double* zpart= (double*)alloc((u64)2*nblk*8);
  double* xpart= (double*)alloc((u64)2*nblk*128*8);
  char* zbase = p;                             // zero-init group (per layer)
  double* xsum = (double*)alloc(2*128*8);
  double* Z    = (double*)alloc(256);
  size_t zbytes = (size_t)(p - zbase);
  double* c    = (double*)alloc(2*128*8);
  double* c0   = (double*)alloc(256);

  const int gE = (E + 255)/256;
  const int gWave = (N + 3)/4;

  // ---- graph prep (layer-invariant): y=0 -> dst=user (ei_i2u), y=1 -> dst=item (ei_u2i)
  hipMemsetAsync(deg, 0, (u64)2*N*4, stream);
  k_hist<<<dim3(gE,2),256,0,stream>>>(ei_i2u + E, ei_u2i + E, deg, N, E);
  k_scan<<<dim3(1,2),1024,0,stream>>>(deg, off, cur, N);
  k_fill<<<dim3(gE,2),256,0,stream>>>(ei_i2u, ei_u2i, cur, csr, N, E);

  for (int L=0; L<2; ++L){
    const float* xu = L ? outU : x_user;
    const float* xi = L ? (outU + (u64)N*D) : x_item;
    hipMemsetAsync(zbase, 0, zbytes, stream);
    k_prepM<<<dim3(128,2),128,0,stream>>>(qkv_w, qkv_b, L, M, u1, b0);
    k_gemm<1><<<dim3(nblk,2),256,0,stream>>>(xu, xi, qkv_w, qkv_b, M, u1, b0, self_w, self_b,
                                             deg, c, c0, v, l, zpart, xpart, s, outU, L, N);
    k_red<<<dim3(8,2),256,0,stream>>>(xpart, zpart, xsum, Z, nblk);
    k_coef<<<dim3(2,1),128,0,stream>>>(xsum, qkv_w, qkv_b, rel_w, L, E, c, c0);
    k_gemm<0><<<dim3(nblk,2),256,0,stream>>>(xu, xi, qkv_w, qkv_b, M, u1, b0, self_w, self_b,
                                             deg, c, c0, v, l, zpart, xpart, s, outU, L, N);
    k_agg<<<dim3(gWave,2),256,0,stream>>>(off, csr, s, v, l, Z, outU, N, E);
  }
  k_gemm<2><<<dim3(nblk,2),256,0,stream>>>(nullptr, nullptr, qkv_w, qkv_b, M, u1, b0, self_w, self_b,
                                           deg, c, c0, v, l, zpart, xpart, s, outU, 0, N);
}

// Round 5
// 852.757 us; speedup vs baseline: 3.7099x; 1.5299x over previous
//
#include <hip/hip_runtime.h>

#define D 128
typedef unsigned long long u64;
typedef __attribute__((ext_vector_type(8))) short bf16x8;
typedef __attribute__((ext_vector_type(4))) float f32x4;

__device__ __forceinline__ unsigned short f2bf(float f){
  unsigned int u = __float_as_uint(f);
  return (unsigned short)((u + 0x7FFFu + ((u >> 16) & 1u)) >> 16);
}
__device__ __forceinline__ float bf2f(unsigned short h){
  return __uint_as_float(((unsigned int)h) << 16);
}
__device__ __forceinline__ void cvt8(float4 a0, float4 a1, bf16x8 &hi, bf16x8 &lo){
  float f[8] = {a0.x,a0.y,a0.z,a0.w,a1.x,a1.y,a1.z,a1.w};
#pragma unroll
  for (int j=0;j<8;++j){
    unsigned short h = f2bf(f[j]);
    hi[j] = (short)h;
    lo[j] = (short)f2bf(f[j] - bf2f(h));
  }
}

// ---------------- graph prep ----------------

__global__ __launch_bounds__(256) void k_hist(const int* __restrict__ dstA, const int* __restrict__ dstB,
                                              int* __restrict__ deg, int N, int E){
  int e = blockIdx.x*256 + threadIdx.x;
  int y = blockIdx.y;
  const int* d = y ? dstB : dstA;
  if (e < E) atomicAdd(&deg[(u64)y*N + d[e]], 1);
}

__global__ __launch_bounds__(1024) void k_scan(const int* __restrict__ degA, int* __restrict__ offA,
                                               int* __restrict__ curA, int n){
  int y = blockIdx.y;
  const int* deg = degA + (u64)y*n;
  int* off = offA + (u64)y*(n+1);
  int* cur = curA + (u64)y*n;
  __shared__ int wsum[16];
  __shared__ int carry_sh;
  int t = threadIdx.x, lane = t & 63, wid = t >> 6;
  if (t == 0) carry_sh = 0;
  __syncthreads();
  const int TILE = 4096;
  for (int base = 0; base < n; base += TILE){
    int idx = base + t*4;
    int v0 = (idx+0 < n)? deg[idx+0] : 0;
    int v1 = (idx+1 < n)? deg[idx+1] : 0;
    int v2 = (idx+2 < n)? deg[idx+2] : 0;
    int v3 = (idx+3 < n)? deg[idx+3] : 0;
    int tsum = v0+v1+v2+v3;
    int sc = tsum;                       // inclusive wave scan
    for (int o=1;o<64;o<<=1){ int u = __shfl_up(sc,o); if (lane>=o) sc += u; }
    if (lane == 63) wsum[wid] = sc;
    __syncthreads();
    if (wid == 0 && lane < 16){
      int ws = wsum[lane];
      int s2 = ws;
      for (int o=1;o<16;o<<=1){ int u = __shfl_up(s2,o); if (lane>=o) s2 += u; }
      wsum[lane] = s2 - ws;              // exclusive wave offsets
    }
    __syncthreads();
    int excl = carry_sh + wsum[wid] + sc - tsum;
    int run = excl;
    if (idx+0 < n){ off[idx+0]=run; cur[idx+0]=run; run+=v0; }
    if (idx+1 < n){ off[idx+1]=run; cur[idx+1]=run; run+=v1; }
    if (idx+2 < n){ off[idx+2]=run; cur[idx+2]=run; run+=v2; }
    if (idx+3 < n){ off[idx+3]=run; cur[idx+3]=run; run+=v3; }
    __syncthreads();
    if (t == 1023) carry_sh = excl + tsum;
    __syncthreads();
  }
  if (t == 0) off[n] = carry_sh;
}

__global__ __launch_bounds__(256) void k_fill(const int* __restrict__ eiA, const int* __restrict__ eiB,
                                              int* __restrict__ cur, int* __restrict__ csr, int N, int E){
  int e = blockIdx.x*256 + threadIdx.x;
  int y = blockIdx.y;
  const int* ei = y ? eiB : eiA;
  if (e < E){
    int p = atomicAdd(&cur[(u64)y*N + ei[E + e]], 1);
    csr[(u64)y*E + p] = ei[e];
  }
}

// ---------------- weight packing (bf16 hi/lo split, MFMA-fragment order) ----------------
// fragment halfword index o for (k,col): ct=col>>4, ks=k>>5, lane=(col&15)|(((k>>3)&3)<<4), j=k&7
// o = ct*2048 + ks*512 + lane*8 + j

__global__ __launch_bounds__(256) void k_pack(const float* __restrict__ W0, int wstride,
                                              unsigned short* __restrict__ ph, unsigned short* __restrict__ pl){
  int o = blockIdx.x*256 + threadIdx.x;      // 0..16383
  int y = blockIdx.y;
  int j = o & 7, lane = (o>>3) & 63, ks = (o>>9) & 3, ct = o >> 11;
  int k = ks*32 + ((lane>>4)<<3) + j;
  int col = (ct<<4) + (lane&15);
  float wv = W0[(u64)y*wstride + k*128 + col];
  unsigned short h = f2bf(wv);
  ph[(u64)y*16384 + o] = h;
  pl[(u64)y*16384 + o] = f2bf(wv - bf2f(h));
}

// M = Wq@Wk^T (packed bf16 hi/lo); u1 = Wq@bk + Wk@bq ; b0 = bq.bk
__global__ __launch_bounds__(128) void k_prepM(const float* __restrict__ qkv_w, const float* __restrict__ qkv_b,
                                               int L, unsigned short* __restrict__ MH, unsigned short* __restrict__ ML,
                                               float* __restrict__ u1, float* __restrict__ b0){
  int y = blockIdx.y;
  const float* Wq = qkv_w + (u64)((L*2 + y)*3 + 0)*D*D;
  const float* Wk = qkv_w + (u64)((L*2 + y)*3 + 1)*D*D;
  const float* bq = qkv_b + (u64)((L*2 + y)*3 + 0)*D;
  const float* bk = qkv_b + (u64)((L*2 + y)*3 + 1)*D;
  int a = blockIdx.x, b = threadIdx.x;       // M[a][b], a = k-index, b = col
  __shared__ float qrow[128];
  qrow[b] = Wq[a*128+b];
  __syncthreads();
  const float* krow = Wk + b*128;
  float acc = 0.f;
  for (int j=0;j<128;++j) acc += qrow[j]*krow[j];
  int o = (b>>4)*2048 + (a>>5)*512 + (((b&15)|(((a>>3)&3)<<4)))*8 + (a&7);
  unsigned short h = f2bf(acc);
  MH[(u64)y*16384 + o] = h;
  ML[(u64)y*16384 + o] = f2bf(acc - bf2f(h));
  if (b == 0){
    float s1 = 0.f;
    for (int j=0;j<128;++j) s1 += Wq[a*128+j]*bk[j] + Wk[a*128+j]*bq[j];
    u1[y*D + a] = s1;
    if (a == 0){
      float z = 0.f;
      for (int j=0;j<128;++j) z += bq[j]*bk[j];
      b0[y] = z;
    }
  }
}

// ---------------- f64 logit coefficients ----------------

__global__ __launch_bounds__(128) void k_coef(const double* __restrict__ xsum, const float* __restrict__ qkv_w,
                                              const float* __restrict__ qkv_b, const float* __restrict__ rel_w,
                                              int L, int E, double* __restrict__ c, double* __restrict__ c0){
  int t = blockIdx.x;       // src node type whose coefficients we compute
  const float* Wk = qkv_w + (u64)((L*2 + (1-t))*3 + 1)*D*D;
  const float* bk = qkv_b + (u64)((L*2 + (1-t))*3 + 1)*D;
  const float* Wq = qkv_w + (u64)((L*2 + t)*3 + 0)*D*D;
  const float* bq = qkv_b + (u64)((L*2 + t)*3 + 0)*D;
  const float* rel = rel_w + (u64)(L*2 + t)*D*D;
  const double* xs0 = xsum + (1-t)*128;

  __shared__ double sh[128];
  __shared__ double xs[128];
  int j = threadIdx.x;
  xs[j] = xs0[j];
  __syncthreads();
  double ks = (double)E * (double)bk[j];
  for (int d=0; d<128; ++d) ks += xs[d] * (double)Wk[d*128+j];
  sh[j] = ks;
  __syncthreads();
  double tmp = 0.0;
  for (int cc=0; cc<128; ++cc) tmp += (double)rel[j*128+cc] * sh[cc];
  __syncthreads();
  sh[j] = tmp;
  __syncthreads();
  const double scale = 0.08838834764831843;  // 1/sqrt(128)
  double cv = 0.0;
  for (int k2=0;k2<128;++k2) cv += (double)Wq[j*128+k2] * sh[k2];
  c[t*128 + j] = cv * scale;
  if (j == 0){
    double z = 0.0;
    for (int k2=0;k2<128;++k2) z += (double)bq[k2] * sh[k2];
    c0[t] = z * scale;
  }
}

// ---------------- MFMA GEMM: 128 rows x 128 cols per block, 4 waves x 2 strips ----------------
// MODE 0: v = x@Wv + bv ; s[row] = x[row].c + c0 (f64, fused)
// MODE 1: T = x@M ; l = scale*(rowdot(T+u1,x) + b0) ; zpart + xsum partials
// MODE 2: io = io@Wself + bself + io (in place)

template<int MODE>
__global__ __launch_bounds__(256,2) void k_mf(
    const float* __restrict__ x0, const float* __restrict__ x1,
    const unsigned short* __restrict__ packH, const unsigned short* __restrict__ packL,
    const float* __restrict__ bias0, int bias_stride,
    const float* __restrict__ u1, const float* __restrict__ b0,
    const int* __restrict__ deg, const double* __restrict__ c, const double* __restrict__ c0,
    float* __restrict__ vout, float* __restrict__ lo_out,
    double* __restrict__ zpart, double* __restrict__ xpart, double* __restrict__ s,
    float* __restrict__ io, int N)
{
  __shared__ unsigned short shWh[16384];      // 32 KB
  __shared__ unsigned short shWl[16384];      // 32 KB
  __shared__ double csh[128];
  __shared__ float fsh[128];                  // bias (MODE0/2) or u1 (MODE1)
  __shared__ float xred[512];                 // MODE1 cross-wave xsum reduce
  __shared__ double zsh[4];

  int y = blockIdx.y;
  int t = threadIdx.x;
  const float* x = (MODE==2) ? (io + (u64)y*N*D) : (y ? x1 : x0);

  {
    const uint4* gh = (const uint4*)(packH + (u64)y*16384);
    const uint4* gl = (const uint4*)(packL + (u64)y*16384);
    uint4* lh = (uint4*)shWh; uint4* ll = (uint4*)shWl;
#pragma unroll
    for (int i=0;i<8;++i){ lh[t + i*256] = gh[t + i*256]; ll[t + i*256] = gl[t + i*256]; }
    if (MODE==0 && t < 128) csh[t] = c[y*128 + t];
    if (t < 128){
      if (MODE==1) fsh[t] = u1[y*D + t];
      else         fsh[t] = bias0[(u64)y*bias_stride + t];
    }
  }
  __syncthreads();

  int w = t >> 6, lane = t & 63;
  int g = lane >> 4, cb = lane & 15;
  int strip0 = blockIdx.x*128 + w*32;          // strip A: rows strip0..+15 ; strip B: +16..+31
  int rA = strip0 + cb, rB = rA + 16;
  const float* xA = x + (u64)(rA < N ? rA : N-1)*D + g*8;
  const float* xB = x + (u64)(rB < N ? rB : N-1)*D + g*8;

  f32x4 accA[8], accB[8];
#pragma unroll
  for (int i=0;i<8;++i){
#pragma unroll
    for (int j=0;j<4;++j){ accA[i][j] = 0.f; accB[i][j] = 0.f; }
  }
  double saccA = 0.0, saccB = 0.0;

  const bf16x8* WH = (const bf16x8*)shWh;
  const bf16x8* WL = (const bf16x8*)shWl;

#pragma unroll
  for (int ks=0; ks<4; ++ks){
    float4 a0 = *(const float4*)(xA + ks*32);
    float4 a1 = *(const float4*)(xA + ks*32 + 4);
    float4 bb0 = *(const float4*)(xB + ks*32);
    float4 bb1 = *(const float4*)(xB + ks*32 + 4);
    bf16x8 Ah, Al, Bh, Bl;
    cvt8(a0, a1, Ah, Al);
    cvt8(bb0, bb1, Bh, Bl);
    if (MODE == 0){
      const double* cp = csh + ks*32 + g*8;
      saccA += (double)a0.x*cp[0] + (double)a0.y*cp[1] + (double)a0.z*cp[2] + (double)a0.w*cp[3]
             + (double)a1.x*cp[4] + (double)a1.y*cp[5] + (double)a1.z*cp[6] + (double)a1.w*cp[7];
      saccB += (double)bb0.x*cp[0] + (double)bb0.y*cp[1] + (double)bb0.z*cp[2] + (double)bb0.w*cp[3]
             + (double)bb1.x*cp[4] + (double)bb1.y*cp[5] + (double)bb1.z*cp[6] + (double)bb1.w*cp[7];
    }
#pragma unroll
    for (int ct=0; ct<8; ++ct){
      bf16x8 wh = WH[(ct*4 + ks)*64 + lane];
      bf16x8 wl = WL[(ct*4 + ks)*64 + lane];
      accA[ct] = __builtin_amdgcn_mfma_f32_16x16x32_bf16(Ah, wh, accA[ct], 0, 0, 0);
      accA[ct] = __builtin_amdgcn_mfma_f32_16x16x32_bf16(Ah, wl, accA[ct], 0, 0, 0);
      accA[ct] = __builtin_amdgcn_mfma_f32_16x16x32_bf16(Al, wh, accA[ct], 0, 0, 0);
      accB[ct] = __builtin_amdgcn_mfma_f32_16x16x32_bf16(Bh, wh, accB[ct], 0, 0, 0);
      accB[ct] = __builtin_amdgcn_mfma_f32_16x16x32_bf16(Bh, wl, accB[ct], 0, 0, 0);
      accB[ct] = __builtin_amdgcn_mfma_f32_16x16x32_bf16(Bl, wh, accB[ct], 0, 0, 0);
    }
  }

  // C/D layout: col = ct*16 + (lane&15), row = strip_base + (lane>>4)*4 + reg   [m89-verified]
  if (MODE == 0){
    float* outp = vout + (u64)y*N*D;
#pragma unroll
    for (int ct=0; ct<8; ++ct){
      int col = ct*16 + cb;
      float bv = fsh[col];
#pragma unroll
      for (int r=0;r<4;++r){
        int rowA = strip0 + g*4 + r;
        if (rowA < N) outp[(u64)rowA*D + col] = accA[ct][r] + bv;
        int rowB = strip0 + 16 + g*4 + r;
        if (rowB < N) outp[(u64)rowB*D + col] = accB[ct][r] + bv;
      }
    }
    saccA += __shfl_xor(saccA, 16); saccA += __shfl_xor(saccA, 32);
    saccB += __shfl_xor(saccB, 16); saccB += __shfl_xor(saccB, 32);
    if (g == 0){
      double cc0 = c0[y];
      if (rA < N) s[(u64)y*N + rA] = saccA + cc0;
      if (rB < N) s[(u64)y*N + rB] = saccB + cc0;
    }
  } else if (MODE == 1){
    const int* dgp = deg + (u64)y*N;
    float axs[8];
#pragma unroll
    for (int i=0;i<8;++i) axs[i] = 0.f;
    double esum = 0.0;
    float b0v = b0[y];

#define STRIP_EP(ACC, BASE)                                                        \
    {                                                                              \
      float dacc[4] = {0.f,0.f,0.f,0.f};                                           \
      float dgv[4];                                                                \
      _Pragma("unroll")                                                            \
      for (int r=0;r<4;++r){                                                       \
        int row = (BASE) + g*4 + r;                                                \
        dgv[r] = (row < N) ? (float)dgp[row] : 0.f;                                \
      }                                                                            \
      _Pragma("unroll")                                                            \
      for (int ct=0;ct<8;++ct){                                                    \
        int col = ct*16 + cb;                                                      \
        float uv = fsh[col];                                                       \
        _Pragma("unroll")                                                          \
        for (int r=0;r<4;++r){                                                     \
          int row = (BASE) + g*4 + r;                                              \
          float xv = (row < N) ? x[(u64)row*D + col] : 0.f;                        \
          dacc[r] += (ACC[ct][r] + uv) * xv;                                       \
          axs[ct] = fmaf(dgv[r], xv, axs[ct]);                                     \
        }                                                                          \
      }                                                                            \
      _Pragma("unroll")                                                            \
      for (int o=1;o<16;o<<=1){                                                    \
        _Pragma("unroll")                                                          \
        for (int r=0;r<4;++r) dacc[r] += __shfl_xor(dacc[r], o);                   \
      }                                                                            \
      if (cb == 0){                                                                \
        _Pragma("unroll")                                                          \
        for (int r=0;r<4;++r){                                                     \
          int row = (BASE) + g*4 + r;                                              \
          if (row < N){                                                            \
            float lval = 0.08838834764831843f * (dacc[r] + b0v);                   \
            lo_out[(u64)y*N + row] = lval;                                         \
            esum += (double)expf(lval);                                            \
          }                                                                        \
        }                                                                          \
      }                                                                            \
    }

    STRIP_EP(accA, strip0)
    STRIP_EP(accB, strip0 + 16)
#undef STRIP_EP

#pragma unroll
    for (int i=0;i<8;++i){ axs[i] += __shfl_xor(axs[i], 16); axs[i] += __shfl_xor(axs[i], 32); }
    if (g == 0){
#pragma unroll
      for (int i=0;i<8;++i) xred[w*128 + i*16 + cb] = axs[i];
    }
#pragma unroll
    for (int o=1;o<64;o<<=1) esum += __shfl_xor(esum, o);
    if (lane == 0) zsh[w] = esum;
    __syncthreads();
    if (t < 128){
      double xs = (double)xred[t] + (double)xred[128+t] + (double)xred[256+t] + (double)xred[384+t];
      xpart[((u64)y*gridDim.x + blockIdx.x)*128 + t] = xs;
    }
    if (t == 0) zpart[(u64)y*gridDim.x + blockIdx.x] = zsh[0]+zsh[1]+zsh[2]+zsh[3];
  } else {
    float* outp = io + (u64)y*N*D;
#pragma unroll
    for (int ct=0; ct<8; ++ct){
      int col = ct*16 + cb;
      float bv = fsh[col];
#pragma unroll
      for (int r=0;r<4;++r){
        int rowA = strip0 + g*4 + r;
        if (rowA < N){
          float xv = x[(u64)rowA*D + col];
          outp[(u64)rowA*D + col] = accA[ct][r] + bv + xv;
        }
        int rowB = strip0 + 16 + g*4 + r;
        if (rowB < N){
          float xv = x[(u64)rowB*D + col];
          outp[(u64)rowB*D + col] = accB[ct][r] + bv + xv;
        }
      }
    }
  }
}

// ---- reduce xsum partials + Z ----
__global__ __launch_bounds__(256) void k_red(const double* __restrict__ xpart, const double* __restrict__ zpart,
                                             double* __restrict__ xsum, double* __restrict__ Z, int nblk){
  int y = blockIdx.y, slice = blockIdx.x;
  int col = threadIdx.x & 127, half = threadIdx.x >> 7;
  double a = 0.0;
  for (int b = slice*2 + half; b < nblk; b += 16)
    a += xpart[((u64)y*nblk + b)*128 + col];
  __shared__ double sh[256];
  sh[threadIdx.x] = a;
  __syncthreads();
  if (half == 0) atomicAdd(&xsum[y*128 + col], a + sh[col + 128]);
  if (slice == 0){
    double z = 0.0;
    for (int i = threadIdx.x; i < nblk; i += 256) z += zpart[(u64)y*nblk + i];
#pragma unroll
    for (int o=32;o;o>>=1) z += __shfl_xor(z, o);
    __shared__ double zsh[4];
    if ((threadIdx.x & 63) == 0) zsh[threadIdx.x >> 6] = z;
    __syncthreads();
    if (threadIdx.x == 0) Z[y] = zsh[0]+zsh[1]+zsh[2]+zsh[3];
  }
}

// ---------------- aggregation: one wave per dst node, lane-parallel softmax ----------------

__global__ __launch_bounds__(256) void k_agg(const int* __restrict__ off, const int* __restrict__ csr,
                                             const double* __restrict__ s, const float* __restrict__ v,
                                             const float* __restrict__ l, const double* __restrict__ Z,
                                             float* __restrict__ out, int N, int E){
  int gid = blockIdx.x*256 + threadIdx.x;
  int n = gid >> 6, lane = gid & 63;
  if (n >= N) return;
  int y = blockIdx.y;
  const int* offp = off + (u64)y*(N+1);
  const int* csrp = csr + (u64)y*E;
  const double* sp = s + (u64)(1-y)*N;       // logits live on src type = other type
  const float* vsrc = v + (u64)(1-y)*N*D;
  const float* vself = v + (u64)y*N*D;

  int beg = offp[n], end = offp[n+1];
  int deg = end - beg;
  float ax = 0.f, ay = 0.f;
  if (deg > 0){
    if (deg <= 64){
      bool act = lane < deg;
      int idx = csrp[beg + (act ? lane : 0)];
      double sv = sp[idx];
      if (!act) sv = -1e300;
      double m = sv;
#pragma unroll
      for (int o=32;o;o>>=1){ double t = __shfl_xor(m, o); m = t > m ? t : m; }
      float e = act ? expf((float)(sv - m)) : 0.f;
      float Zl = e;
#pragma unroll
      for (int o=32;o;o>>=1) Zl += __shfl_xor(Zl, o);
      float wgt = e / (Zl * (float)deg);
      for (int k=0;k<deg;++k){
        float wk = __shfl(wgt, k);
        int sk = __shfl(idx, k);
        float2 vv = ((const float2*)(vsrc + (u64)sk*D))[lane];
        ax = fmaf(wk, vv.x, ax);
        ay = fmaf(wk, vv.y, ay);
      }
    } else {
      double m = -1e300;
      for (int e=beg;e<end;++e){ double sv = sp[csrp[e]]; m = sv > m ? sv : m; }
      float Zl = 0.f;
      for (int e=beg;e<end;++e) Zl += expf((float)(sp[csrp[e]] - m));
      float inv = 1.f / (Zl * (float)deg);
      for (int e=beg;e<end;++e){
        int src = csrp[e];
        float w2 = expf((float)(sp[src] - m)) * inv;
        float2 vv = ((const float2*)(vsrc + (u64)src*D))[lane];
        ax = fmaf(w2, vv.x, ax);
        ay = fmaf(w2, vv.y, ay);
      }
    }
  }
  float a = expf(l[(u64)y*N + n]) / (float)(Z[y]);
  float2 vs = ((const float2*)(vself + (u64)n*D))[lane];
  ax = fmaf(a, vs.x, ax);
  ay = fmaf(a, vs.y, ay);
  ((float2*)(out + (u64)y*N*D + (u64)n*D))[lane] = make_float2(ax, ay);
}

// ---------------- launch ----------------

extern "C" void kernel_launch(void* const* d_in, const int* in_sizes, int n_in,
                              void* d_out, int out_size, void* d_ws, size_t ws_size,
                              hipStream_t stream){
  const float* x_user = (const float*)d_in[0];
  const float* x_item = (const float*)d_in[1];
  const int*   ei_u2i = (const int*)d_in[2];   // [2,E]: row0 src(user), row1 dst(item)
  const int*   ei_i2u = (const int*)d_in[3];   // [2,E]: row0 src(item), row1 dst(user)
  const float* qkv_w  = (const float*)d_in[4]; // [2,2,3,D,D]
  const float* qkv_b  = (const float*)d_in[5]; // [2,2,3,D]
  const float* rel_w  = (const float*)d_in[6]; // [2,2,D,D]
  const float* self_w = (const float*)d_in[7]; // [2,D,D]
  const float* self_b = (const float*)d_in[8]; // [2,D]

  const int N = in_sizes[0] / D;
  const int E = in_sizes[2] / 2;
  float* outU = (float*)d_out;                 // [2][N][D] contiguous (user then item)

  const int nblk = (N + 127)/128;

  char* p = (char*)d_ws;
  auto alloc = [&](size_t bytes)->char*{ char* r = p; p += (bytes + 255)/256*256; return r; };
  float*  v    = (float*) alloc((u64)2*N*D*4);
  double* s    = (double*)alloc((u64)2*N*8);
  float*  l    = (float*) alloc((u64)2*N*4);
  int*    deg  = (int*)   alloc((u64)2*N*4);
  int*    off  = (int*)   alloc((u64)2*(N+1)*4);
  int*    cur  = (int*)   alloc((u64)2*N*4);
  int*    csr  = (int*)   alloc((u64)2*E*4);
  unsigned short* WvH = (unsigned short*)alloc(2*16384*2);
  unsigned short* WvL = (unsigned short*)alloc(2*16384*2);
  unsigned short* MH  = (unsigned short*)alloc(2*16384*2);
  unsigned short* ML  = (unsigned short*)alloc(2*16384*2);
  unsigned short* SH  = (unsigned short*)alloc(2*16384*2);
  unsigned short* SL  = (unsigned short*)alloc(2*16384*2);
  float*  u1   = (float*) alloc(2*D*4);
  float*  b0   = (float*) alloc(256);
  double* zpart= (double*)alloc((u64)2*nblk*8);
  double* xpart= (double*)alloc((u64)2*nblk*128*8);
  char* zbase = p;                             // zero-init group (per layer)
  double* xsum = (double*)alloc(2*128*8);
  double* Z    = (double*)alloc(256);
  size_t zbytes = (size_t)(p - zbase);
  double* c    = (double*)alloc(2*128*8);
  double* c0   = (double*)alloc(256);

  const int gE = (E + 255)/256;
  const int gWave = (N + 3)/4;

  // ---- graph prep (layer-invariant): y=0 -> dst=user (ei_i2u), y=1 -> dst=item (ei_u2i)
  hipMemsetAsync(deg, 0, (u64)2*N*4, stream);
  k_hist<<<dim3(gE,2),256,0,stream>>>(ei_i2u + E, ei_u2i + E, deg, N, E);
  k_scan<<<dim3(1,2),1024,0,stream>>>(deg, off, cur, N);
  k_fill<<<dim3(gE,2),256,0,stream>>>(ei_i2u, ei_u2i, cur, csr, N, E);
  k_pack<<<dim3(64,2),256,0,stream>>>(self_w, D*D, SH, SL);

  for (int L=0; L<2; ++L){
    const float* xu = L ? outU : x_user;
    const float* xi = L ? (outU + (u64)N*D) : x_item;
    hipMemsetAsync(zbase, 0, zbytes, stream);
    k_prepM<<<dim3(128,2),128,0,stream>>>(qkv_w, qkv_b, L, MH, ML, u1, b0);
    k_pack<<<dim3(64,2),256,0,stream>>>(qkv_w + (u64)(L*6+2)*D*D, 3*D*D, WvH, WvL);
    k_mf<1><<<dim3(nblk,2),256,0,stream>>>(xu, xi, MH, ML, self_b, D,
                                           u1, b0, deg, c, c0, v, l, zpart, xpart, s, outU, N);
    k_red<<<dim3(8,2),256,0,stream>>>(xpart, zpart, xsum, Z, nblk);
    k_coef<<<dim3(2,1),128,0,stream>>>(xsum, qkv_w, qkv_b, rel_w, L, E, c, c0);
    k_mf<0><<<dim3(nblk,2),256,0,stream>>>(xu, xi, WvH, WvL, qkv_b + (u64)(L*6+2)*D, 3*D,
                                           u1, b0, deg, c, c0, v, l, zpart, xpart, s, outU, N);
    k_agg<<<dim3(gWave,2),256,0,stream>>>(off, csr, s, v, l, Z, outU, N, E);
  }
  k_mf<2><<<dim3(nblk,2),256,0,stream>>>(nullptr, nullptr, SH, SL, self_b, D,
                                         u1, b0, deg, c, c0, v, l, zpart, xpart, s, outU, N);
}

// Round 7
// 788.667 us; speedup vs baseline: 4.0114x; 1.0813x over previous
//
#include <hip/hip_runtime.h>

#define D 128
typedef unsigned long long u64;
typedef __attribute__((ext_vector_type(8))) short bf16x8;
typedef __attribute__((ext_vector_type(4))) float f32x4;

__device__ __forceinline__ unsigned short f2bf(float f){   // round-to-nearest-even
  unsigned int u = __float_as_uint(f);
  return (unsigned short)((u + 0x7FFFu + ((u >> 16) & 1u)) >> 16);
}
__device__ __forceinline__ float bf2f(unsigned short h){
  return __uint_as_float(((unsigned int)h) << 16);
}
// round-nearest split: hi = rn16(f), lo = rn16(f - hi)  -> |f - hi - lo| ~ 2^-18 |f|
__device__ __forceinline__ void cvt8(float4 a0, float4 a1, bf16x8 &hi, bf16x8 &lo){
  float f[8] = {a0.x,a0.y,a0.z,a0.w,a1.x,a1.y,a1.z,a1.w};
#pragma unroll
  for (int j=0;j<8;++j){
    unsigned short h = f2bf(f[j]);
    hi[j] = (short)h;
    lo[j] = (short)f2bf(f[j] - bf2f(h));
  }
}

// ---------------- graph prep ----------------

__global__ __launch_bounds__(256) void k_hist(const int* __restrict__ dstA, const int* __restrict__ dstB,
                                              int* __restrict__ deg, int N, int E){
  int e = blockIdx.x*256 + threadIdx.x;
  int y = blockIdx.y;
  const int* d = y ? dstB : dstA;
  if (e < E) atomicAdd(&deg[(u64)y*N + d[e]], 1);
}

__global__ __launch_bounds__(1024) void k_scan(const int* __restrict__ degA, int* __restrict__ offA,
                                               int* __restrict__ curA, int n){
  int y = blockIdx.y;
  const int* deg = degA + (u64)y*n;
  int* off = offA + (u64)y*(n+1);
  int* cur = curA + (u64)y*n;
  __shared__ int wsum[16];
  __shared__ int carry_sh;
  int t = threadIdx.x, lane = t & 63, wid = t >> 6;
  if (t == 0) carry_sh = 0;
  __syncthreads();
  const int TILE = 4096;
  for (int base = 0; base < n; base += TILE){
    int idx = base + t*4;
    int v0 = (idx+0 < n)? deg[idx+0] : 0;
    int v1 = (idx+1 < n)? deg[idx+1] : 0;
    int v2 = (idx+2 < n)? deg[idx+2] : 0;
    int v3 = (idx+3 < n)? deg[idx+3] : 0;
    int tsum = v0+v1+v2+v3;
    int sc = tsum;                       // inclusive wave scan
    for (int o=1;o<64;o<<=1){ int u = __shfl_up(sc,o); if (lane>=o) sc += u; }
    if (lane == 63) wsum[wid] = sc;
    __syncthreads();
    if (wid == 0 && lane < 16){
      int ws = wsum[lane];
      int s2 = ws;
      for (int o=1;o<16;o<<=1){ int u = __shfl_up(s2,o); if (lane>=o) s2 += u; }
      wsum[lane] = s2 - ws;              // exclusive wave offsets
    }
    __syncthreads();
    int excl = carry_sh + wsum[wid] + sc - tsum;
    int run = excl;
    if (idx+0 < n){ off[idx+0]=run; cur[idx+0]=run; run+=v0; }
    if (idx+1 < n){ off[idx+1]=run; cur[idx+1]=run; run+=v1; }
    if (idx+2 < n){ off[idx+2]=run; cur[idx+2]=run; run+=v2; }
    if (idx+3 < n){ off[idx+3]=run; cur[idx+3]=run; run+=v3; }
    __syncthreads();
    if (t == 1023) carry_sh = excl + tsum;
    __syncthreads();
  }
  if (t == 0) off[n] = carry_sh;
}

__global__ __launch_bounds__(256) void k_fill(const int* __restrict__ eiA, const int* __restrict__ eiB,
                                              int* __restrict__ cur, int* __restrict__ csr, int N, int E){
  int e = blockIdx.x*256 + threadIdx.x;
  int y = blockIdx.y;
  const int* ei = y ? eiB : eiA;
  if (e < E){
    int p = atomicAdd(&cur[(u64)y*N + ei[E + e]], 1);
    csr[(u64)y*E + p] = ei[e];
  }
}

// ---------------- weight packing (bf16 hi/lo split, MFMA-fragment order) ----------------
// fragment halfword index o for (k,col): ct=col>>4, ks=k>>5, lane=(col&15)|(((k>>3)&3)<<4), j=k&7
// o = ct*2048 + ks*512 + lane*8 + j

__global__ __launch_bounds__(256) void k_pack(const float* __restrict__ W0, int wstride,
                                              unsigned short* __restrict__ ph, unsigned short* __restrict__ pl){
  int o = blockIdx.x*256 + threadIdx.x;      // 0..16383
  int y = blockIdx.y;
  int j = o & 7, lane = (o>>3) & 63, ks = (o>>9) & 3, ct = o >> 11;
  int k = ks*32 + ((lane>>4)<<3) + j;
  int col = (ct<<4) + (lane&15);
  float wv = W0[(u64)y*wstride + k*128 + col];
  unsigned short h = f2bf(wv);
  ph[(u64)y*16384 + o] = h;
  pl[(u64)y*16384 + o] = f2bf(wv - bf2f(h));
}

// M = Wq@Wk^T (packed bf16 hi/lo); u1 = Wq@bk + Wk@bq ; b0 = bq.bk
__global__ __launch_bounds__(128) void k_prepM(const float* __restrict__ qkv_w, const float* __restrict__ qkv_b,
                                               int L, unsigned short* __restrict__ MH, unsigned short* __restrict__ ML,
                                               float* __restrict__ u1, float* __restrict__ b0){
  int y = blockIdx.y;
  const float* Wq = qkv_w + (u64)((L*2 + y)*3 + 0)*D*D;
  const float* Wk = qkv_w + (u64)((L*2 + y)*3 + 1)*D*D;
  const float* bq = qkv_b + (u64)((L*2 + y)*3 + 0)*D;
  const float* bk = qkv_b + (u64)((L*2 + y)*3 + 1)*D;
  int a = blockIdx.x, b = threadIdx.x;       // M[a][b], a = k-index, b = col
  __shared__ float qrow[128];
  qrow[b] = Wq[a*128+b];
  __syncthreads();
  const float* krow = Wk + b*128;
  float acc = 0.f;
  for (int j=0;j<128;++j) acc += qrow[j]*krow[j];
  int o = (b>>4)*2048 + (a>>5)*512 + (((b&15)|(((a>>3)&3)<<4)))*8 + (a&7);
  unsigned short h = f2bf(acc);
  MH[(u64)y*16384 + o] = h;
  ML[(u64)y*16384 + o] = f2bf(acc - bf2f(h));
  if (b == 0){
    float s1 = 0.f;
    for (int j=0;j<128;++j) s1 += Wq[a*128+j]*bk[j] + Wk[a*128+j]*bq[j];
    u1[y*D + a] = s1;
    if (a == 0){
      float z = 0.f;
      for (int j=0;j<128;++j) z += bq[j]*bk[j];
      b0[y] = z;
    }
  }
}

// ---------------- f64 logit coefficients ----------------

__global__ __launch_bounds__(128) void k_coef(const double* __restrict__ xsum, const float* __restrict__ qkv_w,
                                              const float* __restrict__ qkv_b, const float* __restrict__ rel_w,
                                              int L, int E, double* __restrict__ c, double* __restrict__ c0){
  int t = blockIdx.x;       // src node type whose coefficients we compute
  const float* Wk = qkv_w + (u64)((L*2 + (1-t))*3 + 1)*D*D;
  const float* bk = qkv_b + (u64)((L*2 + (1-t))*3 + 1)*D;
  const float* Wq = qkv_w + (u64)((L*2 + t)*3 + 0)*D*D;
  const float* bq = qkv_b + (u64)((L*2 + t)*3 + 0)*D;
  const float* rel = rel_w + (u64)(L*2 + t)*D*D;
  const double* xs0 = xsum + (1-t)*128;

  __shared__ double sh[128];
  __shared__ double xs[128];
  int j = threadIdx.x;
  xs[j] = xs0[j];
  __syncthreads();
  double ks = (double)E * (double)bk[j];
  for (int d=0; d<128; ++d) ks += xs[d] * (double)Wk[d*128+j];
  sh[j] = ks;
  __syncthreads();
  double tmp = 0.0;
  for (int cc=0; cc<128; ++cc) tmp += (double)rel[j*128+cc] * sh[cc];
  __syncthreads();
  sh[j] = tmp;
  __syncthreads();
  const double scale = 0.08838834764831843;  // 1/sqrt(128)
  double cv = 0.0;
  for (int k2=0;k2<128;++k2) cv += (double)Wq[j*128+k2] * sh[k2];
  c[t*128 + j] = cv * scale;
  if (j == 0){
    double z = 0.0;
    for (int k2=0;k2<128;++k2) z += (double)bq[k2] * sh[k2];
    c0[t] = z * scale;
  }
}

// ---------------- MFMA GEMM: 128 rows x 128 cols per block, 4 waves x 2 strips ----------------
// Operands SWAPPED vs naive: acc = mfma(Wfrag, Xfrag) -> lane holds out[x_row = lane&15 (+strip)]
// [col = ct*16 + (lane>>4)*4 + reg]  => 4 consecutive cols per lane: float4 epilogues.
// MODE 0: v = x@Wv + bv (f32) ; s[row] = x[row].c + c0 (f64, fused)
// MODE 1: T = x@M ; l = scale*(rowdot(T+u1,x) + b0) ; zpart + xsum partials
// MODE 2: io = io@Wself + bself + io (in place)

template<int MODE>
__global__ __launch_bounds__(256,2) void k_mf(
    const float* __restrict__ x0, const float* __restrict__ x1,
    const unsigned short* __restrict__ packH, const unsigned short* __restrict__ packL,
    const float* __restrict__ bias0, int bias_stride,
    const float* __restrict__ u1, const float* __restrict__ b0,
    const int* __restrict__ deg, const double* __restrict__ c, const double* __restrict__ c0,
    float* __restrict__ vout, float* __restrict__ lo_out,
    double* __restrict__ zpart, double* __restrict__ xpart, double* __restrict__ s,
    float* __restrict__ io, int N)
{
  __shared__ unsigned short shWh[16384];      // 32 KB
  __shared__ unsigned short shWl[16384];      // 32 KB
  __shared__ double csh[128];
  __shared__ float fsh[128];                  // bias (MODE0/2) or u1 (MODE1)
  __shared__ float xred[512];
  __shared__ double zsh[4];

  int y = blockIdx.y;
  int t = threadIdx.x;
  const float* x = (MODE==2) ? (io + (u64)y*N*D) : (y ? x1 : x0);

  {
    const uint4* gh = (const uint4*)(packH + (u64)y*16384);
    const uint4* gl = (const uint4*)(packL + (u64)y*16384);
    uint4* lh = (uint4*)shWh; uint4* ll = (uint4*)shWl;
#pragma unroll
    for (int i=0;i<8;++i){ lh[t + i*256] = gh[t + i*256]; ll[t + i*256] = gl[t + i*256]; }
    if (MODE==0 && t < 128) csh[t] = c[y*128 + t];
    if (t < 128){
      if (MODE==1) fsh[t] = u1[y*D + t];
      else         fsh[t] = bias0[(u64)y*bias_stride + t];
    }
  }
  __syncthreads();

  int w = t >> 6, lane = t & 63;
  int g = lane >> 4, cb = lane & 15;
  int strip0 = blockIdx.x*128 + w*32;          // strip A: rows strip0..+15 ; strip B: +16..+31
  int rA = strip0 + cb, rB = rA + 16;
  const float* xA = x + (u64)(rA < N ? rA : N-1)*D;
  const float* xB = x + (u64)(rB < N ? rB : N-1)*D;

  f32x4 accA[8], accB[8];
#pragma unroll
  for (int i=0;i<8;++i){
#pragma unroll
    for (int j=0;j<4;++j){ accA[i][j] = 0.f; accB[i][j] = 0.f; }
  }
  double saccA = 0.0, saccB = 0.0;

  const bf16x8* WH = (const bf16x8*)shWh;
  const bf16x8* WL = (const bf16x8*)shWl;

#pragma unroll
  for (int ks=0; ks<4; ++ks){
    float4 a0  = *(const float4*)(xA + ks*32 + g*8);
    float4 a1  = *(const float4*)(xA + ks*32 + g*8 + 4);
    float4 bb0 = *(const float4*)(xB + ks*32 + g*8);
    float4 bb1 = *(const float4*)(xB + ks*32 + g*8 + 4);
    bf16x8 Ah, Al, Bh, Bl;
    cvt8(a0, a1, Ah, Al);
    cvt8(bb0, bb1, Bh, Bl);
    if (MODE == 0){
      const double* cp = csh + ks*32 + g*8;
      saccA += (double)a0.x*cp[0] + (double)a0.y*cp[1] + (double)a0.z*cp[2] + (double)a0.w*cp[3]
             + (double)a1.x*cp[4] + (double)a1.y*cp[5] + (double)a1.z*cp[6] + (double)a1.w*cp[7];
      saccB += (double)bb0.x*cp[0] + (double)bb0.y*cp[1] + (double)bb0.z*cp[2] + (double)bb0.w*cp[3]
             + (double)bb1.x*cp[4] + (double)bb1.y*cp[5] + (double)bb1.z*cp[6] + (double)bb1.w*cp[7];
    }
#pragma unroll
    for (int ct=0; ct<8; ++ct){
      bf16x8 wh = WH[(ct*4 + ks)*64 + lane];
      bf16x8 wl = WL[(ct*4 + ks)*64 + lane];
      accA[ct] = __builtin_amdgcn_mfma_f32_16x16x32_bf16(wh, Ah, accA[ct], 0, 0, 0);
      accA[ct] = __builtin_amdgcn_mfma_f32_16x16x32_bf16(wl, Ah, accA[ct], 0, 0, 0);
      accA[ct] = __builtin_amdgcn_mfma_f32_16x16x32_bf16(wh, Al, accA[ct], 0, 0, 0);
      accB[ct] = __builtin_amdgcn_mfma_f32_16x16x32_bf16(wh, Bh, accB[ct], 0, 0, 0);
      accB[ct] = __builtin_amdgcn_mfma_f32_16x16x32_bf16(wl, Bh, accB[ct], 0, 0, 0);
      accB[ct] = __builtin_amdgcn_mfma_f32_16x16x32_bf16(wh, Bl, accB[ct], 0, 0, 0);
    }
  }

  if (MODE == 0){
    float* outp = vout + (u64)y*N*D;
#pragma unroll
    for (int ct=0; ct<8; ++ct){
      float4 bv = ((const float4*)fsh)[ct*4 + g];
      if (rA < N){
        float4 o = make_float4(accA[ct][0]+bv.x, accA[ct][1]+bv.y, accA[ct][2]+bv.z, accA[ct][3]+bv.w);
        *(float4*)(outp + (u64)rA*D + ct*16 + g*4) = o;
      }
      if (rB < N){
        float4 o = make_float4(accB[ct][0]+bv.x, accB[ct][1]+bv.y, accB[ct][2]+bv.z, accB[ct][3]+bv.w);
        *(float4*)(outp + (u64)rB*D + ct*16 + g*4) = o;
      }
    }
    saccA += __shfl_xor(saccA, 16); saccA += __shfl_xor(saccA, 32);
    saccB += __shfl_xor(saccB, 16); saccB += __shfl_xor(saccB, 32);
    if (g == 0){
      double cc0 = c0[y];
      if (rA < N) s[(u64)y*N + rA] = saccA + cc0;
      if (rB < N) s[(u64)y*N + rB] = saccB + cc0;
    }
  } else if (MODE == 1){
    const int* dgp = deg + (u64)y*N;
    float dgA = (rA < N) ? (float)dgp[rA] : 0.f;
    float dgB = (rB < N) ? (float)dgp[rB] : 0.f;
    float dotA = 0.f, dotB = 0.f;
    f32x4 axs[8];
#pragma unroll
    for (int i=0;i<8;++i){ axs[i][0]=0.f; axs[i][1]=0.f; axs[i][2]=0.f; axs[i][3]=0.f; }
#pragma unroll
    for (int ct=0; ct<8; ++ct){
      float4 uv = ((const float4*)fsh)[ct*4 + g];
      float4 xa = *(const float4*)(xA + ct*16 + g*4);
      float4 xb = *(const float4*)(xB + ct*16 + g*4);
      dotA += (accA[ct][0]+uv.x)*xa.x + (accA[ct][1]+uv.y)*xa.y
            + (accA[ct][2]+uv.z)*xa.z + (accA[ct][3]+uv.w)*xa.w;
      dotB += (accB[ct][0]+uv.x)*xb.x + (accB[ct][1]+uv.y)*xb.y
            + (accB[ct][2]+uv.z)*xb.z + (accB[ct][3]+uv.w)*xb.w;
      axs[ct][0] = fmaf(dgA, xa.x, fmaf(dgB, xb.x, axs[ct][0]));
      axs[ct][1] = fmaf(dgA, xa.y, fmaf(dgB, xb.y, axs[ct][1]));
      axs[ct][2] = fmaf(dgA, xa.z, fmaf(dgB, xb.z, axs[ct][2]));
      axs[ct][3] = fmaf(dgA, xa.w, fmaf(dgB, xb.w, axs[ct][3]));
    }
    dotA += __shfl_xor(dotA, 16); dotA += __shfl_xor(dotA, 32);
    dotB += __shfl_xor(dotB, 16); dotB += __shfl_xor(dotB, 32);
    double esum = 0.0;
    if (g == 0){
      float b0v = b0[y];
      if (rA < N){
        float lv = 0.08838834764831843f * (dotA + b0v);
        lo_out[(u64)y*N + rA] = lv; esum += (double)expf(lv);
      }
      if (rB < N){
        float lv = 0.08838834764831843f * (dotB + b0v);
        lo_out[(u64)y*N + rB] = lv; esum += (double)expf(lv);
      }
    }
#pragma unroll
    for (int o=1;o<64;o<<=1) esum += __shfl_xor(esum, o);
    if (lane == 0) zsh[w] = esum;
#pragma unroll
    for (int ct=0;ct<8;++ct){
#pragma unroll
      for (int o=1;o<16;o<<=1){
        axs[ct][0] += __shfl_xor(axs[ct][0], o);
        axs[ct][1] += __shfl_xor(axs[ct][1], o);
        axs[ct][2] += __shfl_xor(axs[ct][2], o);
        axs[ct][3] += __shfl_xor(axs[ct][3], o);
      }
    }
    if (cb == 0){
#pragma unroll
      for (int ct=0;ct<8;++ct)
        *(float4*)(xred + w*128 + ct*16 + g*4) = make_float4(axs[ct][0],axs[ct][1],axs[ct][2],axs[ct][3]);
    }
    __syncthreads();
    if (t < 128){
      double xs = (double)xred[t] + (double)xred[128+t] + (double)xred[256+t] + (double)xred[384+t];
      xpart[((u64)y*gridDim.x + blockIdx.x)*128 + t] = xs;
    }
    if (t == 0) zpart[(u64)y*gridDim.x + blockIdx.x] = zsh[0]+zsh[1]+zsh[2]+zsh[3];
  } else {
    float* outp = io + (u64)y*N*D;
#pragma unroll
    for (int ct=0; ct<8; ++ct){
      float4 bv = ((const float4*)fsh)[ct*4 + g];
      if (rA < N){
        float4 xv = *(const float4*)(xA + ct*16 + g*4);
        float4 o = make_float4(accA[ct][0]+bv.x+xv.x, accA[ct][1]+bv.y+xv.y,
                               accA[ct][2]+bv.z+xv.z, accA[ct][3]+bv.w+xv.w);
        *(float4*)(outp + (u64)rA*D + ct*16 + g*4) = o;
      }
      if (rB < N){
        float4 xv = *(const float4*)(xB + ct*16 + g*4);
        float4 o = make_float4(accB[ct][0]+bv.x+xv.x, accB[ct][1]+bv.y+xv.y,
                               accB[ct][2]+bv.z+xv.z, accB[ct][3]+bv.w+xv.w);
        *(float4*)(outp + (u64)rB*D + ct*16 + g*4) = o;
      }
    }
  }
}

// ---- reduce xsum partials + Z ----
__global__ __launch_bounds__(256) void k_red(const double* __restrict__ xpart, const double* __restrict__ zpart,
                                             double* __restrict__ xsum, double* __restrict__ Z, int nblk){
  int y = blockIdx.y, slice = blockIdx.x;
  int col = threadIdx.x & 127, half = threadIdx.x >> 7;
  double a = 0.0;
  for (int b = slice*2 + half; b < nblk; b += 16)
    a += xpart[((u64)y*nblk + b)*128 + col];
  __shared__ double sh[256];
  sh[threadIdx.x] = a;
  __syncthreads();
  if (half == 0) atomicAdd(&xsum[y*128 + col], a + sh[col + 128]);
  if (slice == 0){
    double z = 0.0;
    for (int i = threadIdx.x; i < nblk; i += 256) z += zpart[(u64)y*nblk + i];
#pragma unroll
    for (int o=32;o;o>>=1) z += __shfl_xor(z, o);
    __shared__ double zsh[4];
    if ((threadIdx.x & 63) == 0) zsh[threadIdx.x >> 6] = z;
    __syncthreads();
    if (threadIdx.x == 0) Z[y] = zsh[0]+zsh[1]+zsh[2]+zsh[3];
  }
}

// ---------------- aggregation: 2 nodes per wave (32-lane halves), f32 v, float4 gather ----------------

__global__ __launch_bounds__(256) void k_agg(const int* __restrict__ off, const int* __restrict__ csr,
                                             const double* __restrict__ s, const float* __restrict__ v,
                                             const float* __restrict__ l, const double* __restrict__ Z,
                                             float* __restrict__ out, int N, int E){
  int t = threadIdx.x;
  int n = blockIdx.x*8 + (t >> 5);
  if (n >= N) return;
  int sl = t & 31;
  int hb = t & 32;                           // half base within the wave
  int y = blockIdx.y;
  const int* offp = off + (u64)y*(N+1);
  const int* csrp = csr + (u64)y*E;
  const double* sp = s + (u64)(1-y)*N;       // logits live on src type = other type
  const float* vsrc = v + (u64)(1-y)*N*D;
  const float* vself = v + (u64)y*N*D;

  int beg = offp[n], end = offp[n+1];
  int deg = end - beg;
  float ax=0.f, ay=0.f, az=0.f, aw=0.f;
  if (deg > 0){
    if (deg <= 32){
      bool act = sl < deg;
      int idx = csrp[beg + (act ? sl : 0)];
      double sv = act ? sp[idx] : -1e300;
      double m = sv;
#pragma unroll
      for (int o=16;o;o>>=1){ double u = __shfl_xor(m, o); m = u > m ? u : m; }
      float e = act ? expf((float)(sv - m)) : 0.f;
      float Zl = e;
#pragma unroll
      for (int o=16;o;o>>=1) Zl += __shfl_xor(Zl, o);
      float wgt = e / (Zl * (float)deg);
      for (int k=0;k<deg;++k){
        float wk = __shfl(wgt, hb + k);
        int sk = __shfl(idx, hb + k);
        float4 vv = *(const float4*)(vsrc + (u64)sk*D + sl*4);
        ax = fmaf(wk, vv.x, ax); ay = fmaf(wk, vv.y, ay);
        az = fmaf(wk, vv.z, az); aw = fmaf(wk, vv.w, aw);
      }
    } else {
      double m = -1e300;
      for (int e2=beg;e2<end;++e2){ double sv = sp[csrp[e2]]; m = sv > m ? sv : m; }
      float Zl = 0.f;
      for (int e2=beg;e2<end;++e2) Zl += expf((float)(sp[csrp[e2]] - m));
      float inv = 1.f / (Zl * (float)deg);
      for (int e2=beg;e2<end;++e2){
        int sk = csrp[e2];
        float wk = expf((float)(sp[sk] - m)) * inv;
        float4 vv = *(const float4*)(vsrc + (u64)sk*D + sl*4);
        ax = fmaf(wk, vv.x, ax); ay = fmaf(wk, vv.y, ay);
        az = fmaf(wk, vv.z, az); aw = fmaf(wk, vv.w, aw);
      }
    }
  }
  float a = expf(l[(u64)y*N + n]) / (float)(Z[y]);
  float4 vs = *(const float4*)(vself + (u64)n*D + sl*4);
  ax = fmaf(a, vs.x, ax); ay = fmaf(a, vs.y, ay);
  az = fmaf(a, vs.z, az); aw = fmaf(a, vs.w, aw);
  *(float4*)(out + (u64)y*N*D + (u64)n*D + sl*4) = make_float4(ax, ay, az, aw);
}

// ---------------- launch ----------------

extern "C" void kernel_launch(void* const* d_in, const int* in_sizes, int n_in,
                              void* d_out, int out_size, void* d_ws, size_t ws_size,
                              hipStream_t stream){
  const float* x_user = (const float*)d_in[0];
  const float* x_item = (const float*)d_in[1];
  const int*   ei_u2i = (const int*)d_in[2];   // [2,E]: row0 src(user), row1 dst(item)
  const int*   ei_i2u = (const int*)d_in[3];   // [2,E]: row0 src(item), row1 dst(user)
  const float* qkv_w  = (const float*)d_in[4]; // [2,2,3,D,D]
  const float* qkv_b  = (const float*)d_in[5]; // [2,2,3,D]
  const float* rel_w  = (const float*)d_in[6]; // [2,2,D,D]
  const float* self_w = (const float*)d_in[7]; // [2,D,D]
  const float* self_b = (const float*)d_in[8]; // [2,D]

  const int N = in_sizes[0] / D;
  const int E = in_sizes[2] / 2;
  float* outU = (float*)d_out;                 // [2][N][D] contiguous (user then item)

  const int nblk = (N + 127)/128;

  char* p = (char*)d_ws;
  auto alloc = [&](size_t bytes)->char*{ char* r = p; p += (bytes + 255)/256*256; return r; };
  float*  v    = (float*) alloc((u64)2*N*D*4);
  double* s    = (double*)alloc((u64)2*N*8);
  float*  l    = (float*) alloc((u64)2*N*4);
  int*    deg  = (int*)   alloc((u64)2*N*4);
  int*    off  = (int*)   alloc((u64)2*(N+1)*4);
  int*    cur  = (int*)   alloc((u64)2*N*4);
  int*    csr  = (int*)   alloc((u64)2*E*4);
  unsigned short* WvH = (unsigned short*)alloc(2*16384*2);
  unsigned short* WvL = (unsigned short*)alloc(2*16384*2);
  unsigned short* MH  = (unsigned short*)alloc(2*16384*2);
  unsigned short* ML  = (unsigned short*)alloc(2*16384*2);
  unsigned short* SH  = (unsigned short*)alloc(2*16384*2);
  unsigned short* SL  = (unsigned short*)alloc(2*16384*2);
  float*  u1   = (float*) alloc(2*D*4);
  float*  b0   = (float*) alloc(256);
  double* zpart= (double*)alloc((u64)2*nblk*8);
  double* xpart= (double*)alloc((u64)2*nblk*128*8);
  char* zbase = p;                             // zero-init group (per layer)
  double* xsum = (double*)alloc(2*128*8);
  double* Z    = (double*)alloc(256);
  size_t zbytes = (size_t)(p - zbase);
  double* c    = (double*)alloc(2*128*8);
  double* c0   = (double*)alloc(256);

  const int gE = (E + 255)/256;
  const int gAgg = (N + 7)/8;

  // ---- graph prep (layer-invariant): y=0 -> dst=user (ei_i2u), y=1 -> dst=item (ei_u2i)
  hipMemsetAsync(deg, 0, (u64)2*N*4, stream);
  k_hist<<<dim3(gE,2),256,0,stream>>>(ei_i2u + E, ei_u2i + E, deg, N, E);
  k_scan<<<dim3(1,2),1024,0,stream>>>(deg, off, cur, N);
  k_fill<<<dim3(gE,2),256,0,stream>>>(ei_i2u, ei_u2i, cur, csr, N, E);
  k_pack<<<dim3(64,2),256,0,stream>>>(self_w, D*D, SH, SL);

  for (int L=0; L<2; ++L){
    const float* xu = L ? outU : x_user;
    const float* xi = L ? (outU + (u64)N*D) : x_item;
    hipMemsetAsync(zbase, 0, zbytes, stream);
    k_prepM<<<dim3(128,2),128,0,stream>>>(qkv_w, qkv_b, L, MH, ML, u1, b0);
    k_pack<<<dim3(64,2),256,0,stream>>>(qkv_w + (u64)(L*6+2)*D*D, 3*D*D, WvH, WvL);
    k_mf<1><<<dim3(nblk,2),256,0,stream>>>(xu, xi, MH, ML, self_b, D,
                                           u1, b0, deg, c, c0, v, l, zpart, xpart, s, outU, N);
    k_red<<<dim3(8,2),256,0,stream>>>(xpart, zpart, xsum, Z, nblk);
    k_coef<<<dim3(2,1),128,0,stream>>>(xsum, qkv_w, qkv_b, rel_w, L, E, c, c0);
    k_mf<0><<<dim3(nblk,2),256,0,stream>>>(xu, xi, WvH, WvL, qkv_b + (u64)(L*6+2)*D, 3*D,
                                           u1, b0, deg, c, c0, v, l, zpart, xpart, s, outU, N);
    k_agg<<<dim3(gAgg,2),256,0,stream>>>(off, csr, s, v, l, Z, outU, N, E);
  }
  k_mf<2><<<dim3(nblk,2),256,0,stream>>>(nullptr, nullptr, SH, SL, self_b, D,
                                         u1, b0, deg, c, c0, v, l, zpart, xpart, s, outU, N);
}